// Round 8
// baseline (277.681 us; speedup 1.0000x reference)
//
#include <hip/hip_runtime.h>
#include <hip/hip_bf16.h>

#define NNETS 10
#define BATCH 8192

typedef __attribute__((ext_vector_type(8)))  short  short8;
typedef __attribute__((ext_vector_type(16))) float  f32x16;

// ---------------- workspace layout (bytes) ----------------
// (x is no longer packed: L0 reads raw fp32 x and converts in-register)
// w0pack: [n(10)][kc(49)][ct(4)][hl(2)][lane(64)][j(8)]
// w7pack: [n(10)][kc(8)][ct(25)][hl(2)][lane(64)][j(8)]
// w1pack: [n(10)][kc(8)][ct(2)][hl(2)][lane(64)][j(8)]
// w6pack: [n(10)][kc(4)][ct(4)][hl(2)][lane(64)][j(8)]
#define W0PACK_OFF   0UL
#define W0PACK_BYTES (10UL*49*4*2*64*8*2)
#define W7PACK_OFF   (W0PACK_OFF + W0PACK_BYTES)
#define W7PACK_BYTES (10UL*8*25*2*64*8*2)
#define W1PACK_OFF   (W7PACK_OFF + W7PACK_BYTES)
#define W1PACK_BYTES (10UL*8*2*2*64*8*2)
#define W6PACK_OFF   (W1PACK_OFF + W1PACK_BYTES)
#define W6PACK_BYTES (10UL*4*4*2*64*8*2)
#define TOTAL_WS     (W6PACK_OFF + W6PACK_BYTES)

// pack grid ranges (blocks of 256) — weights only now
#define PW0_BLOCKS 490
#define PW7_BLOCKS 500
#define PW1_BLOCKS 40
#define PW6_BLOCKS 40
#define PACK_GRID  (PW0_BLOCKS + PW7_BLOCKS + PW1_BLOCKS + PW6_BLOCKS)

// ---------------- helpers ----------------
__device__ __forceinline__ float fast_tanh(float x) {
    // 1 - 2/(1+e^{2x}); raw v_rcp (no slow div sequence). Saturates exactly:
    // e=inf -> rcp(inf)=0 -> 1;  e=0 -> 1-2 = -1.
    float e = __expf(2.f * x);
    return 1.f - 2.f * __builtin_amdgcn_rcpf(1.f + e);
}
__device__ __forceinline__ unsigned short bf16_rne(float v) {
    unsigned u = __float_as_uint(v);
    unsigned r = (u + 0x7FFFu + ((u >> 16) & 1u)) >> 16;
    return (unsigned short)r;
}
__device__ __forceinline__ float bf16_to_f(unsigned short h) {
    return __uint_as_float(((unsigned)h) << 16);
}
__device__ __forceinline__ unsigned split_pack(float v) {
    unsigned short h = bf16_rne(v);
    unsigned short l = bf16_rne(v - bf16_to_f(h));
    return (unsigned)h | ((unsigned)l << 16);
}
__device__ __forceinline__ short f2bf(float v) {
    __hip_bfloat16 b = __float2bfloat16(v);   // RNE; compiler emits cvt(_pk)
    return *reinterpret_cast<short*>(&b);
}
__device__ __forceinline__ short8 cvt8(float4 a, float4 b) {
    short8 r;
    r[0] = f2bf(a.x); r[1] = f2bf(a.y); r[2] = f2bf(a.z); r[3] = f2bf(a.w);
    r[4] = f2bf(b.x); r[5] = f2bf(b.y); r[6] = f2bf(b.z); r[7] = f2bf(b.w);
    return r;
}

// ---------------- merged weight-pack kernel ----------------
__device__ __forceinline__ void pack_w0_body(int tid, const float* __restrict__ W0,
                                             unsigned short* __restrict__ wp) {
    if (tid >= 10 * 49 * 4 * 64) return;
    int lane = tid & 63; int t2 = tid >> 6;
    int ct = t2 % 4;  t2 /= 4;
    int kc = t2 % 49; int n = t2 / 49;
    int col = ct * 32 + (lane & 31);
    int kb  = kc * 16 + 8 * (lane >> 5);
    short8 H, L;
#pragma unroll
    for (int j = 0; j < 8; ++j) {
        float v = W0[((size_t)n * 784 + kb + j) * 128 + col];
        unsigned short h = bf16_rne(v);
        H[j] = (short)h;
        L[j] = (short)bf16_rne(v - bf16_to_f(h));
    }
    short8* dst = reinterpret_cast<short8*>(wp + (size_t)((n * 49 + kc) * 4 + ct) * 1024) + lane;
    dst[0]  = H;
    dst[64] = L;
}

__device__ __forceinline__ void pack_w7_body(int tid, const float* __restrict__ W7,
                                             unsigned short* __restrict__ wp) {
    if (tid >= 10 * 8 * 25 * 64) return;
    int lane = tid & 63; int t2 = tid >> 6;
    int ct = t2 % 25; t2 /= 25;
    int kc = t2 % 8;  int n = t2 / 8;
    int col = ct * 32 + (lane & 31);
    int kb  = kc * 16 + 8 * (lane >> 5);
    short8 H, L;
#pragma unroll
    for (int j = 0; j < 8; ++j) {
        float v = (col < 784) ? W7[((size_t)n * 128 + kb + j) * 784 + col] : 0.f;
        unsigned short h = bf16_rne(v);
        H[j] = (short)h;
        L[j] = (short)bf16_rne(v - bf16_to_f(h));
    }
    short8* dst = reinterpret_cast<short8*>(wp + (size_t)((n * 8 + kc) * 25 + ct) * 1024) + lane;
    dst[0]  = H;
    dst[64] = L;
}

__device__ __forceinline__ void pack_w1_body(int tid, const float* __restrict__ W1,
                                             unsigned short* __restrict__ wp) {
    if (tid >= 10 * 8 * 2 * 64) return;
    int lane = tid & 63; int t2 = tid >> 6;
    int ct = t2 % 2; t2 /= 2;
    int kc = t2 % 8; int n = t2 / 8;
    int col = ct * 32 + (lane & 31);
    int kb  = kc * 16 + 8 * (lane >> 5);
    short8 H, L;
#pragma unroll
    for (int j = 0; j < 8; ++j) {
        float v = W1[((size_t)n * 128 + kb + j) * 64 + col];
        unsigned short h = bf16_rne(v);
        H[j] = (short)h;
        L[j] = (short)bf16_rne(v - bf16_to_f(h));
    }
    short8* dst = reinterpret_cast<short8*>(wp + (size_t)((n * 8 + kc) * 2 + ct) * 1024) + lane;
    dst[0]  = H;
    dst[64] = L;
}

__device__ __forceinline__ void pack_w6_body(int tid, const float* __restrict__ W6,
                                             unsigned short* __restrict__ wp) {
    if (tid >= 10 * 4 * 4 * 64) return;
    int lane = tid & 63; int t2 = tid >> 6;
    int ct = t2 % 4; t2 /= 4;
    int kc = t2 % 4; int n = t2 / 4;
    int col = ct * 32 + (lane & 31);
    int kb  = kc * 16 + 8 * (lane >> 5);
    short8 H, L;
#pragma unroll
    for (int j = 0; j < 8; ++j) {
        float v = W6[((size_t)n * 64 + kb + j) * 128 + col];
        unsigned short h = bf16_rne(v);
        H[j] = (short)h;
        L[j] = (short)bf16_rne(v - bf16_to_f(h));
    }
    short8* dst = reinterpret_cast<short8*>(wp + (size_t)((n * 4 + kc) * 4 + ct) * 1024) + lane;
    dst[0]  = H;
    dst[64] = L;
}

__global__ __launch_bounds__(256)
void pack_all_kernel(const float* __restrict__ W0, const float* __restrict__ W1,
                     const float* __restrict__ W6, const float* __restrict__ W7,
                     unsigned short* __restrict__ ws_u16) {
    int b = blockIdx.x;
    if (b < PW0_BLOCKS) {
        pack_w0_body(b * 256 + threadIdx.x, W0, ws_u16 + W0PACK_OFF / 2);
    } else if (b < PW0_BLOCKS + PW7_BLOCKS) {
        pack_w7_body((b - PW0_BLOCKS) * 256 + threadIdx.x, W7, ws_u16 + W7PACK_OFF / 2);
    } else if (b < PW0_BLOCKS + PW7_BLOCKS + PW1_BLOCKS) {
        pack_w1_body((b - PW0_BLOCKS - PW7_BLOCKS) * 256 + threadIdx.x, W1, ws_u16 + W1PACK_OFF / 2);
    } else {
        pack_w6_body((b - PW0_BLOCKS - PW7_BLOCKS - PW1_BLOCKS) * 256 + threadIdx.x, W6, ws_u16 + W6PACK_OFF / 2);
    }
}

// ---------------- mid layers (fp32 VALU; round-4 proven structure) ----------
template<int ID, int OD, int NO, bool RELU>
__device__ __forceinline__ void midlayer(const float* __restrict__ W,
                                         const float* __restrict__ bias,
                                         const float* bufIn, float* bufOut,
                                         int n, int w, int lane) {
    const int o0 = w * NO;
    if (o0 < OD) {
        float acc[NO];
#pragma unroll
        for (int j = 0; j < NO; ++j) acc[j] = bias[n * OD + o0 + j];
        for (int k = 0; k < ID; ++k) {
            float a = bufIn[k * 65 + lane];
            const float* Wk = W + ((size_t)n * ID + k) * OD + o0;
#pragma unroll
            for (int j = 0; j < NO; ++j) acc[j] = fmaf(a, Wk[j], acc[j]);
        }
#pragma unroll
        for (int j = 0; j < NO; ++j) {
            float v = acc[j];
            if (RELU) v = fmaxf(v, 0.f);
            bufOut[(o0 + j) * 65 + lane] = v;
        }
    }
    __syncthreads();
}

#define MFMA32(A, B, C) __builtin_amdgcn_mfma_f32_32x32x16_bf16(A, B, C, 0, 0, 0)

// ---------------- main fused kernel ----------------
// Structure: r4-proven (HsA+HsB ping-pong, wave-split mids). Known landmines:
// (256,4) launch bound -> VGPR squeeze/spill (r5, -24%); register midlayer
// rewrite (r6, -42%). Keep plain bounds + this structure.
__global__ __launch_bounds__(256)
void fused_ae_mfma_kernel(const float* __restrict__ x,
                          const float* __restrict__ B0,
                          const float* __restrict__ B1,
                          const float* __restrict__ W2, const float* __restrict__ B2,
                          const float* __restrict__ W3, const float* __restrict__ B3,
                          const float* __restrict__ W4, const float* __restrict__ B4,
                          const float* __restrict__ W5, const float* __restrict__ B5,
                          const float* __restrict__ B6,
                          const float* __restrict__ B7,
                          const unsigned short* __restrict__ ws_u16,
                          float* __restrict__ out) {
    __shared__ float HsA[128 * 65];   // 33.3 KB
    __shared__ float HsB[64 * 65];    // 16.6 KB
    unsigned* HsAu = reinterpret_cast<unsigned*>(HsA);

    const int t    = threadIdx.x;
    const int lane = t & 63;
    const int w    = __builtin_amdgcn_readfirstlane(t >> 6);  // wave 0..3

    // XCD swizzle: all 10 nets sharing a y-tile land on the same XCD.
    const int bid = blockIdx.x;
    const int g   = bid & 7;
    const int j8  = bid >> 3;          // 0..159
    const int yb  = (g << 4) + (j8 / 10);
    const int n   = j8 % 10;

    const int cl   = lane & 31;
    const int hf   = lane >> 5;
    const int rtl  = w >> 1;
    const int ct0  = (w & 1) * 2;

    const short8* w0p8 = reinterpret_cast<const short8*>(ws_u16 + W0PACK_OFF / 2);
    const short8* w7p8 = reinterpret_cast<const short8*>(ws_u16 + W7PACK_OFF / 2);
    const short8* w1p8 = reinterpret_cast<const short8*>(ws_u16 + W1PACK_OFF / 2);
    const short8* w6p8 = reinterpret_cast<const short8*>(ws_u16 + W6PACK_OFF / 2);

    // ================= Layer 0: x_hi @ (W0_hi + W0_lo) -> h0 (pk u32), relu ======
    // x read RAW: lane's fragment = 8 consecutive floats of one row (one 64B
    // line per row, 2 lanes/line -> full line utilization), converted via cvt_pk.
    const int rt = yb * 2 + rtl;
    f32x16 acc0, acc1;
#pragma unroll
    for (int i = 0; i < 16; ++i) { acc0[i] = 0.f; acc1[i] = 0.f; }

    const float* xrow = x + (size_t)(rt * 32 + cl) * 784 + 8 * hf;
    const short8* wB = w0p8 + ((size_t)n * 49 * 4 + ct0) * 128 + lane;  // kc stride 512

    float4 xv0 = *(const float4*)(xrow);
    float4 xv1 = *(const float4*)(xrow + 4);
    short8 Ah = cvt8(xv0, xv1);
    short8 Bh0 = wB[0], Bl0 = wB[64], Bh1 = wB[128], Bl1 = wB[192];
    for (int kc = 0; kc < 49; ++kc) {
        short8 nAh, nBh0, nBl0, nBh1, nBl1;
        if (kc < 48) {
            float4 nv0 = *(const float4*)(xrow + (kc + 1) * 16);
            float4 nv1 = *(const float4*)(xrow + (kc + 1) * 16 + 4);
            nAh = cvt8(nv0, nv1);
            const short8* wn = wB + (size_t)(kc + 1) * 512;
            nBh0 = wn[0]; nBl0 = wn[64]; nBh1 = wn[128]; nBl1 = wn[192];
        }
        acc0 = MFMA32(Ah, Bh0, acc0);
        acc0 = MFMA32(Ah, Bl0, acc0);
        acc1 = MFMA32(Ah, Bh1, acc1);
        acc1 = MFMA32(Ah, Bl1, acc1);
        if (kc < 48) { Ah = nAh; Bh0 = nBh0; Bl0 = nBl0; Bh1 = nBh1; Bl1 = nBl1; }
    }
    {
        float b0a = B0[n * 128 + ct0 * 32 + cl];
        float b0b = B0[n * 128 + (ct0 + 1) * 32 + cl];
#pragma unroll
        for (int r2 = 0; r2 < 16; ++r2) {
            int row = rtl * 32 + (r2 & 3) + 8 * (r2 >> 2) + 4 * hf;
            HsAu[(ct0 * 32 + cl) * 65 + row]       = split_pack(fmaxf(acc0[r2] + b0a, 0.f));
            HsAu[((ct0 + 1) * 32 + cl) * 65 + row] = split_pack(fmaxf(acc1[r2] + b0b, 0.f));
        }
    }
    __syncthreads();

    // ================= Layer 1: h0 @ W1 -> h1[64][65] fp32, relu (MFMA) ==========
    {
        const int ctl = w & 1;
        short8 a_hi[8], a_lo[8];
        const int r32 = rtl * 32 + cl;
#pragma unroll
        for (int kc = 0; kc < 8; ++kc) {
            int kb = kc * 16 + 8 * hf;
            short8 H, L;
#pragma unroll
            for (int j = 0; j < 8; ++j) {
                unsigned u = HsAu[(kb + j) * 65 + r32];
                H[j] = (short)(u & 0xFFFFu);
                L[j] = (short)(u >> 16);
            }
            a_hi[kc] = H; a_lo[kc] = L;
        }
        f32x16 acc;
#pragma unroll
        for (int i = 0; i < 16; ++i) acc[i] = 0.f;
        const short8* wb = w1p8 + ((size_t)n * 16 + ctl) * 128 + lane;
#pragma unroll
        for (int kc = 0; kc < 8; ++kc) {
            const short8* bp = wb + (size_t)kc * 256;
            short8 Bh = bp[0], Bl = bp[64];
            acc = MFMA32(a_hi[kc], Bh, acc);
            acc = MFMA32(a_hi[kc], Bl, acc);
            acc = MFMA32(a_lo[kc], Bh, acc);
        }
        __syncthreads();
        float bias = B1[n * 64 + ctl * 32 + cl];
#pragma unroll
        for (int r2 = 0; r2 < 16; ++r2) {
            int row = rtl * 32 + (r2 & 3) + 8 * (r2 >> 2) + 4 * hf;
            HsB[(ctl * 32 + cl) * 65 + row] = fmaxf(acc[r2] + bias, 0.f);
        }
    }
    __syncthreads();

    // ================= Layers 2..5 (fp32 VALU, LDS ping-pong) ====================
    midlayer< 64, 12,  3, true >(W2, B2, HsB, HsA, n, w, lane);  // h1(B)->h2(A)
    midlayer< 12,  3,  1, false>(W3, B3, HsA, HsB, n, w, lane);  // h2(A)->h3(B)
    midlayer<  3, 12,  3, true >(W4, B4, HsB, HsA, n, w, lane);  // h3(B)->h4(A)
    midlayer< 12, 64, 16, true >(W5, B5, HsA, HsB, n, w, lane);  // h4(A)->h5(B)

    // ================= Layer 6: h5 @ W6 -> h6 (packed u32), relu (MFMA) ==========
    {
        short8 a_hi[4], a_lo[4];
        const int r32 = rtl * 32 + cl;
#pragma unroll
        for (int kc = 0; kc < 4; ++kc) {
            int kb = kc * 16 + 8 * hf;
            short8 H, L;
#pragma unroll
            for (int j = 0; j < 8; ++j) {
                float v = HsB[(kb + j) * 65 + r32];
                unsigned short h = bf16_rne(v);
                H[j] = (short)h;
                L[j] = (short)bf16_rne(v - bf16_to_f(h));
            }
            a_hi[kc] = H; a_lo[kc] = L;
        }
        f32x16 acc0b, acc1b;
#pragma unroll
        for (int i = 0; i < 16; ++i) { acc0b[i] = 0.f; acc1b[i] = 0.f; }
        const short8* wb = w6p8 + ((size_t)n * 16 + ct0) * 128 + lane;
#pragma unroll
        for (int kc = 0; kc < 4; ++kc) {
            const short8* bp = wb + (size_t)kc * 512;
            short8 Bh0 = bp[0],   Bl0 = bp[64];
            short8 Bh1 = bp[128], Bl1 = bp[192];
            acc0b = MFMA32(a_hi[kc], Bh0, acc0b);
            acc0b = MFMA32(a_hi[kc], Bl0, acc0b);
            acc0b = MFMA32(a_lo[kc], Bh0, acc0b);
            acc1b = MFMA32(a_hi[kc], Bh1, acc1b);
            acc1b = MFMA32(a_hi[kc], Bl1, acc1b);
            acc1b = MFMA32(a_lo[kc], Bh1, acc1b);
        }
        __syncthreads();   // h5 reads done before HsA h6-write (HsA holds h4; dead)
        float b6a = B6[n * 128 + ct0 * 32 + cl];
        float b6b = B6[n * 128 + (ct0 + 1) * 32 + cl];
#pragma unroll
        for (int r2 = 0; r2 < 16; ++r2) {
            int row = rtl * 32 + (r2 & 3) + 8 * (r2 >> 2) + 4 * hf;
            HsAu[(ct0 * 32 + cl) * 65 + row]       = split_pack(fmaxf(acc0b[r2] + b6a, 0.f));
            HsAu[((ct0 + 1) * 32 + cl) * 65 + row] = split_pack(fmaxf(acc1b[r2] + b6b, 0.f));
        }
    }
    __syncthreads();

    // ================= Layer 7: h6 @ W7, tanh, row-sum ===========================
    short8 a_hi[8], a_lo[8];
    {
        const int r32 = rtl * 32 + cl;
#pragma unroll
        for (int kc = 0; kc < 8; ++kc) {
            int kb = kc * 16 + 8 * hf;
            short8 H, L;
#pragma unroll
            for (int j = 0; j < 8; ++j) {
                unsigned u = HsAu[(kb + j) * 65 + r32];
                H[j] = (short)(u & 0xFFFFu);
                L[j] = (short)(u >> 16);
            }
            a_hi[kc] = H; a_lo[kc] = L;
        }
    }

    float rowsum[16];
#pragma unroll
    for (int i = 0; i < 16; ++i) rowsum[i] = 0.f;

    const short8* w7b = w7p8 + (size_t)n * 8 * 25 * 128 + lane;
    const int ctS = (w & 1) ? 13 : 0;
    const int ctE = (w & 1) ? 25 : 13;
    for (int ct = ctS; ct < ctE; ++ct) {
        // dual accumulator chains: halves the serial MFMA dependency depth
        f32x16 accA, accB;
#pragma unroll
        for (int i = 0; i < 16; ++i) { accA[i] = 0.f; accB[i] = 0.f; }
#pragma unroll
        for (int kc = 0; kc < 8; ++kc) {
            const short8* bp = w7b + (size_t)(kc * 25 + ct) * 128;
            short8 Bh = bp[0], Bl = bp[64];
            accA = MFMA32(a_hi[kc], Bh, accA);
            accB = MFMA32(a_hi[kc], Bl, accB);
            accA = MFMA32(a_lo[kc], Bh, accA);
        }
        int col = ct * 32 + cl;
        if (col < 784) {
            float bias = B7[n * 784 + col];
#pragma unroll
            for (int r2 = 0; r2 < 16; ++r2)
                rowsum[r2] += fast_tanh(accA[r2] + accB[r2] + bias);
        }
    }

#pragma unroll
    for (int r2 = 0; r2 < 16; ++r2) {
        float s = rowsum[r2];
        s += __shfl_xor(s, 1);  s += __shfl_xor(s, 2);  s += __shfl_xor(s, 4);
        s += __shfl_xor(s, 8);  s += __shfl_xor(s, 16);
        rowsum[r2] = s;
    }

    float* Ps = HsB;   // dead
    Ps[t] = 0.f;       // REQUIRED: each wave writes only 32 of its 64 slots below
    __syncthreads();
    if (cl == 0) {
#pragma unroll
        for (int r2 = 0; r2 < 16; ++r2) {
            int row = rtl * 32 + (r2 & 3) + 8 * (r2 >> 2) + 4 * hf;
            Ps[w * 64 + row] = rowsum[r2];
        }
    }
    __syncthreads();
    if (t < 64) {
        float s = Ps[t] + Ps[64 + t] + Ps[128 + t] + Ps[192 + t];
        out[(size_t)(yb * 64 + t) * 10 + n] = s;
    }
}

// ---------------- fp32 fallback if ws too small ----------------
__global__ __launch_bounds__(256)
void fused_ae_fp32_kernel(const float* __restrict__ x,
                          const float* __restrict__ W0, const float* __restrict__ B0,
                          const float* __restrict__ W1, const float* __restrict__ B1,
                          const float* __restrict__ W2, const float* __restrict__ B2,
                          const float* __restrict__ W3, const float* __restrict__ B3,
                          const float* __restrict__ W4, const float* __restrict__ B4,
                          const float* __restrict__ W5, const float* __restrict__ B5,
                          const float* __restrict__ W6, const float* __restrict__ B6,
                          const float* __restrict__ W7, const float* __restrict__ B7,
                          float* __restrict__ out) {
    __shared__ float HsA[128 * 65];
    __shared__ float HsB[64 * 65];
    const int t    = threadIdx.x;
    const int lane = t & 63;
    const int w    = __builtin_amdgcn_readfirstlane(t >> 6);
    const int n    = blockIdx.x;
    const int rowbase = blockIdx.y * 64;

    float acc0[32];
#pragma unroll
    for (int j = 0; j < 32; ++j) acc0[j] = 0.f;
    float* As = HsB;
    const int r   = t >> 2;
    const int kk4 = (t & 3) * 4;
    const float* xrow = x + (size_t)(rowbase + r) * 784;
    for (int kc = 0; kc < 49; ++kc) {
        float4 xv = *(const float4*)(xrow + kc * 16 + kk4);
        As[(kk4 + 0) * 65 + r] = xv.x;
        As[(kk4 + 1) * 65 + r] = xv.y;
        As[(kk4 + 2) * 65 + r] = xv.z;
        As[(kk4 + 3) * 65 + r] = xv.w;
        __syncthreads();
        const float* W0base = W0 + ((size_t)n * 784 + (size_t)kc * 16) * 128 + w * 32;
#pragma unroll
        for (int k = 0; k < 16; ++k) {
            float a = As[k * 65 + lane];
            const float* Wk = W0base + k * 128;
#pragma unroll
            for (int j = 0; j < 32; ++j) acc0[j] = fmaf(a, Wk[j], acc0[j]);
        }
        __syncthreads();
    }
    {
        const float* bb = B0 + n * 128 + w * 32;
#pragma unroll
        for (int j = 0; j < 32; ++j)
            HsA[(w * 32 + j) * 65 + lane] = fmaxf(acc0[j] + bb[j], 0.f);
    }
    __syncthreads();

    midlayer<128, 64, 16, true >(W1, B1, HsA, HsB, n, w, lane);
    midlayer< 64, 12,  3, true >(W2, B2, HsB, HsA, n, w, lane);
    midlayer< 12,  3,  1, false>(W3, B3, HsA, HsB, n, w, lane);
    midlayer<  3, 12,  3, true >(W4, B4, HsB, HsA, n, w, lane);
    midlayer< 12, 64, 16, true >(W5, B5, HsA, HsB, n, w, lane);
    midlayer< 64,128, 32, true >(W6, B6, HsB, HsA, n, w, lane);

    float lane_sum = 0.f;
    const int j0w = w * 196;
    for (int c = 0; c < 7; ++c) {
        const int j0 = j0w + c * 28;
        float acc[28];
        const float* bb = B7 + n * 784 + j0;
#pragma unroll
        for (int j = 0; j < 28; ++j) acc[j] = bb[j];
        for (int k = 0; k < 128; ++k) {
            float a = HsA[k * 65 + lane];
            const float* Wk = W7 + ((size_t)n * 128 + k) * 784 + j0;
#pragma unroll
            for (int j = 0; j < 28; ++j) acc[j] = fmaf(a, Wk[j], acc[j]);
        }
#pragma unroll
        for (int j = 0; j < 28; ++j) lane_sum += fast_tanh(acc[j]);
    }
    float* partial = HsB;
    partial[w * 64 + lane] = lane_sum;
    __syncthreads();
    if (t < 64) {
        float s = partial[t] + partial[64 + t] + partial[128 + t] + partial[192 + t];
        out[(size_t)(rowbase + t) * 10 + n] = s;
    }
}

extern "C" void kernel_launch(void* const* d_in, const int* in_sizes, int n_in,
                              void* d_out, int out_size, void* d_ws, size_t ws_size,
                              hipStream_t stream) {
    (void)in_sizes; (void)n_in; (void)out_size;
    const float* x  = (const float*)d_in[0];
    const float* W0 = (const float*)d_in[1];  const float* B0 = (const float*)d_in[2];
    const float* W1 = (const float*)d_in[3];  const float* B1 = (const float*)d_in[4];
    const float* W2 = (const float*)d_in[5];  const float* B2 = (const float*)d_in[6];
    const float* W3 = (const float*)d_in[7];  const float* B3 = (const float*)d_in[8];
    const float* W4 = (const float*)d_in[9];  const float* B4 = (const float*)d_in[10];
    const float* W5 = (const float*)d_in[11]; const float* B5 = (const float*)d_in[12];
    const float* W6 = (const float*)d_in[13]; const float* B6 = (const float*)d_in[14];
    const float* W7 = (const float*)d_in[15]; const float* B7 = (const float*)d_in[16];
    float* out = (float*)d_out;

    if (ws_size >= TOTAL_WS) {
        unsigned short* ws_u16 = (unsigned short*)d_ws;
        hipLaunchKernelGGL(pack_all_kernel, dim3(PACK_GRID), dim3(256), 0, stream,
                           W0, W1, W6, W7, ws_u16);
        hipLaunchKernelGGL(fused_ae_mfma_kernel, dim3(NNETS * (BATCH / 64)), dim3(256), 0, stream,
                           x, B0, B1, W2, B2, W3, B3, W4, B4, W5, B5, B6, B7, ws_u16, out);
    } else {
        hipLaunchKernelGGL(fused_ae_fp32_kernel, dim3(NNETS, BATCH / 64), dim3(256), 0, stream,
                           x, W0, B0, W1, B1, W2, B2, W3, B3,
                           W4, B4, W5, B5, W6, B6, W7, B7, out);
    }
}

// Round 9
// 277.511 us; speedup vs baseline: 1.0006x; 1.0006x over previous
//
#include <hip/hip_runtime.h>

#define NNETS 10
#define BATCH 8192

typedef __attribute__((ext_vector_type(8)))  short  short8;
typedef __attribute__((ext_vector_type(16))) float  f32x16;

// ---------------- workspace layout (bytes) ----------------
// xpack : [rt(256)][kc(49)][hl(2)][lane(64)][j(8)] bf16  (hi+lo restored; r4's
//         6-MFMA L0 measured fastest: 182us vs 191 hi-only vs 215 raw-x)
// w0pack: [n(10)][kc(49)][ct(4)][hl(2)][lane(64)][j(8)]
// w7pack: [n(10)][kc(8)][ct(25)][hl(2)][lane(64)][j(8)]
// w1pack: [n(10)][kc(8)][ct(2)][hl(2)][lane(64)][j(8)]
// w6pack: [n(10)][kc(4)][ct(4)][hl(2)][lane(64)][j(8)]
#define XPACK_BYTES  (256UL*49*2*64*8*2)
#define W0PACK_OFF   (XPACK_BYTES)
#define W0PACK_BYTES (10UL*49*4*2*64*8*2)
#define W7PACK_OFF   (W0PACK_OFF + W0PACK_BYTES)
#define W7PACK_BYTES (10UL*8*25*2*64*8*2)
#define W1PACK_OFF   (W7PACK_OFF + W7PACK_BYTES)
#define W1PACK_BYTES (10UL*8*2*2*64*8*2)
#define W6PACK_OFF   (W1PACK_OFF + W1PACK_BYTES)
#define W6PACK_BYTES (10UL*4*4*2*64*8*2)
#define TOTAL_WS     (W6PACK_OFF + W6PACK_BYTES)

// pack grid ranges (blocks of 256)
#define PX_BLOCKS  (256 * 7)  // (rt, col-chunk); LDS-staged transpose, hi+lo
#define PW0_BLOCKS 490
#define PW7_BLOCKS 500
#define PW1_BLOCKS 40
#define PW6_BLOCKS 40
#define PACK_GRID  (PX_BLOCKS + PW0_BLOCKS + PW7_BLOCKS + PW1_BLOCKS + PW6_BLOCKS)

// ---------------- helpers ----------------
__device__ __forceinline__ float fast_tanh(float x) {
    // 1 - 2/(1+e^{2x}); raw v_rcp (saves ~8 VALU vs div). Saturates exactly.
    float e = __expf(2.f * x);
    return 1.f - 2.f * __builtin_amdgcn_rcpf(1.f + e);
}
__device__ __forceinline__ unsigned short bf16_rne(float v) {
    unsigned u = __float_as_uint(v);
    unsigned r = (u + 0x7FFFu + ((u >> 16) & 1u)) >> 16;
    return (unsigned short)r;
}
__device__ __forceinline__ float bf16_to_f(unsigned short h) {
    return __uint_as_float(((unsigned)h) << 16);
}
__device__ __forceinline__ unsigned split_pack(float v) {
    unsigned short h = bf16_rne(v);
    unsigned short l = bf16_rne(v - bf16_to_f(h));
    return (unsigned)h | ((unsigned)l << 16);
}

// ---------------- merged pack kernel ----------------
// x-pack: LDS-staged; coalesced reads AND writes; hi+lo.
__device__ __forceinline__ void pack_x_body(int blk, int t, const float* __restrict__ x,
                                            unsigned short* __restrict__ xp,
                                            float (*xs)[113]) {
    const int rt = blk / 7;
    const int c  = blk - rt * 7;          // col-chunk 0..6 (112 cols)
#pragma unroll
    for (int it = 0; it < 4; ++it) {
        int f = t + 256 * it;
        if (f < 896) {
            int row  = f / 28;
            int colq = f - row * 28;
            float4 v = *(const float4*)(x + (size_t)(rt * 32 + row) * 784 + c * 112 + colq * 4);
            xs[row][colq * 4 + 0] = v.x;
            xs[row][colq * 4 + 1] = v.y;
            xs[row][colq * 4 + 2] = v.z;
            xs[row][colq * 4 + 3] = v.w;
        }
    }
    __syncthreads();
    // write phase: 14 dst vectors (7 kc x 2 hl), each 64 lanes x 16B coalesced
    const int lane = t & 63;
    const int sub  = t >> 6;
    const int srow = lane & 31;
    const int skb  = 8 * (lane >> 5);
    for (int idx = sub; idx < 14; idx += 4) {
        int kcl = idx >> 1;
        int hl  = idx & 1;
        short8 V;
#pragma unroll
        for (int j = 0; j < 8; ++j) {
            float v = xs[srow][kcl * 16 + skb + j];
            unsigned short h = bf16_rne(v);
            if (hl == 0) V[j] = (short)h;
            else         V[j] = (short)bf16_rne(v - bf16_to_f(h));
        }
        int kc_global = c * 7 + kcl;
        short8* dst = reinterpret_cast<short8*>(xp) + (size_t)(rt * 49 + kc_global) * 128 + hl * 64 + lane;
        *dst = V;
    }
}

__device__ __forceinline__ void pack_w0_body(int tid, const float* __restrict__ W0,
                                             unsigned short* __restrict__ wp) {
    if (tid >= 10 * 49 * 4 * 64) return;
    int lane = tid & 63; int t2 = tid >> 6;
    int ct = t2 % 4;  t2 /= 4;
    int kc = t2 % 49; int n = t2 / 49;
    int col = ct * 32 + (lane & 31);
    int kb  = kc * 16 + 8 * (lane >> 5);
    short8 H, L;
#pragma unroll
    for (int j = 0; j < 8; ++j) {
        float v = W0[((size_t)n * 784 + kb + j) * 128 + col];
        unsigned short h = bf16_rne(v);
        H[j] = (short)h;
        L[j] = (short)bf16_rne(v - bf16_to_f(h));
    }
    short8* dst = reinterpret_cast<short8*>(wp + (size_t)((n * 49 + kc) * 4 + ct) * 1024) + lane;
    dst[0]  = H;
    dst[64] = L;
}

__device__ __forceinline__ void pack_w7_body(int tid, const float* __restrict__ W7,
                                             unsigned short* __restrict__ wp) {
    if (tid >= 10 * 8 * 25 * 64) return;
    int lane = tid & 63; int t2 = tid >> 6;
    int ct = t2 % 25; t2 /= 25;
    int kc = t2 % 8;  int n = t2 / 8;
    int col = ct * 32 + (lane & 31);
    int kb  = kc * 16 + 8 * (lane >> 5);
    short8 H, L;
#pragma unroll
    for (int j = 0; j < 8; ++j) {
        float v = (col < 784) ? W7[((size_t)n * 128 + kb + j) * 784 + col] : 0.f;
        unsigned short h = bf16_rne(v);
        H[j] = (short)h;
        L[j] = (short)bf16_rne(v - bf16_to_f(h));
    }
    short8* dst = reinterpret_cast<short8*>(wp + (size_t)((n * 8 + kc) * 25 + ct) * 1024) + lane;
    dst[0]  = H;
    dst[64] = L;
}

__device__ __forceinline__ void pack_w1_body(int tid, const float* __restrict__ W1,
                                             unsigned short* __restrict__ wp) {
    if (tid >= 10 * 8 * 2 * 64) return;
    int lane = tid & 63; int t2 = tid >> 6;
    int ct = t2 % 2; t2 /= 2;
    int kc = t2 % 8; int n = t2 / 8;
    int col = ct * 32 + (lane & 31);
    int kb  = kc * 16 + 8 * (lane >> 5);
    short8 H, L;
#pragma unroll
    for (int j = 0; j < 8; ++j) {
        float v = W1[((size_t)n * 128 + kb + j) * 64 + col];
        unsigned short h = bf16_rne(v);
        H[j] = (short)h;
        L[j] = (short)bf16_rne(v - bf16_to_f(h));
    }
    short8* dst = reinterpret_cast<short8*>(wp + (size_t)((n * 8 + kc) * 2 + ct) * 1024) + lane;
    dst[0]  = H;
    dst[64] = L;
}

__device__ __forceinline__ void pack_w6_body(int tid, const float* __restrict__ W6,
                                             unsigned short* __restrict__ wp) {
    if (tid >= 10 * 4 * 4 * 64) return;
    int lane = tid & 63; int t2 = tid >> 6;
    int ct = t2 % 4; t2 /= 4;
    int kc = t2 % 4; int n = t2 / 4;
    int col = ct * 32 + (lane & 31);
    int kb  = kc * 16 + 8 * (lane >> 5);
    short8 H, L;
#pragma unroll
    for (int j = 0; j < 8; ++j) {
        float v = W6[((size_t)n * 64 + kb + j) * 128 + col];
        unsigned short h = bf16_rne(v);
        H[j] = (short)h;
        L[j] = (short)bf16_rne(v - bf16_to_f(h));
    }
    short8* dst = reinterpret_cast<short8*>(wp + (size_t)((n * 4 + kc) * 4 + ct) * 1024) + lane;
    dst[0]  = H;
    dst[64] = L;
}

__global__ __launch_bounds__(256)
void pack_all_kernel(const float* __restrict__ x,
                     const float* __restrict__ W0, const float* __restrict__ W1,
                     const float* __restrict__ W6, const float* __restrict__ W7,
                     unsigned short* __restrict__ ws_u16) {
    __shared__ float xs[32][113];
    int b = blockIdx.x;
    if (b < PX_BLOCKS) {
        pack_x_body(b, threadIdx.x, x, ws_u16, xs);
    } else if (b < PX_BLOCKS + PW0_BLOCKS) {
        pack_w0_body((b - PX_BLOCKS) * 256 + threadIdx.x, W0, ws_u16 + W0PACK_OFF / 2);
    } else if (b < PX_BLOCKS + PW0_BLOCKS + PW7_BLOCKS) {
        pack_w7_body((b - PX_BLOCKS - PW0_BLOCKS) * 256 + threadIdx.x, W7, ws_u16 + W7PACK_OFF / 2);
    } else if (b < PX_BLOCKS + PW0_BLOCKS + PW7_BLOCKS + PW1_BLOCKS) {
        pack_w1_body((b - PX_BLOCKS - PW0_BLOCKS - PW7_BLOCKS) * 256 + threadIdx.x, W1, ws_u16 + W1PACK_OFF / 2);
    } else {
        pack_w6_body((b - PX_BLOCKS - PW0_BLOCKS - PW7_BLOCKS - PW1_BLOCKS) * 256 + threadIdx.x, W6, ws_u16 + W6PACK_OFF / 2);
    }
}

// ---------------- mid layers (fp32 VALU; round-4 proven structure) ----------
template<int ID, int OD, int NO, bool RELU>
__device__ __forceinline__ void midlayer(const float* __restrict__ W,
                                         const float* __restrict__ bias,
                                         const float* bufIn, float* bufOut,
                                         int n, int w, int lane) {
    const int o0 = w * NO;
    if (o0 < OD) {
        float acc[NO];
#pragma unroll
        for (int j = 0; j < NO; ++j) acc[j] = bias[n * OD + o0 + j];
        for (int k = 0; k < ID; ++k) {
            float a = bufIn[k * 65 + lane];
            const float* Wk = W + ((size_t)n * ID + k) * OD + o0;
#pragma unroll
            for (int j = 0; j < NO; ++j) acc[j] = fmaf(a, Wk[j], acc[j]);
        }
#pragma unroll
        for (int j = 0; j < NO; ++j) {
            float v = acc[j];
            if (RELU) v = fmaxf(v, 0.f);
            bufOut[(o0 + j) * 65 + lane] = v;
        }
    }
    __syncthreads();
}

#define MFMA32(A, B, C) __builtin_amdgcn_mfma_f32_32x32x16_bf16(A, B, C, 0, 0, 0)

// ---------------- main fused kernel ----------------
// Structure ledger: r4 structure is the proven optimum (182us). Landmines:
// (256,4) bound -> spill (r5, -24%); register midlayers (r6, -42%); raw-x
// L0 reads (r8, -13%). Keep: packed x hi+lo 6-MFMA L0, HsA/HsB ping-pong,
// rcp-tanh, dual-chain L7, XCD swizzle.
__global__ __launch_bounds__(256)
void fused_ae_mfma_kernel(const float* __restrict__ B0,
                          const float* __restrict__ B1,
                          const float* __restrict__ W2, const float* __restrict__ B2,
                          const float* __restrict__ W3, const float* __restrict__ B3,
                          const float* __restrict__ W4, const float* __restrict__ B4,
                          const float* __restrict__ W5, const float* __restrict__ B5,
                          const float* __restrict__ B6,
                          const float* __restrict__ B7,
                          const unsigned short* __restrict__ ws_u16,
                          float* __restrict__ out) {
    __shared__ float HsA[128 * 65];   // 33.3 KB
    __shared__ float HsB[64 * 65];    // 16.6 KB
    unsigned* HsAu = reinterpret_cast<unsigned*>(HsA);

    const int t    = threadIdx.x;
    const int lane = t & 63;
    const int w    = __builtin_amdgcn_readfirstlane(t >> 6);  // wave 0..3

    // XCD swizzle: all 10 nets sharing a y-tile land on the same XCD.
    const int bid = blockIdx.x;
    const int g   = bid & 7;
    const int j8  = bid >> 3;          // 0..159
    const int yb  = (g << 4) + (j8 / 10);
    const int n   = j8 % 10;

    const int cl   = lane & 31;
    const int hf   = lane >> 5;
    const int rtl  = w >> 1;
    const int ct0  = (w & 1) * 2;

    const short8* xp8  = reinterpret_cast<const short8*>(ws_u16);
    const short8* w0p8 = reinterpret_cast<const short8*>(ws_u16 + W0PACK_OFF / 2);
    const short8* w7p8 = reinterpret_cast<const short8*>(ws_u16 + W7PACK_OFF / 2);
    const short8* w1p8 = reinterpret_cast<const short8*>(ws_u16 + W1PACK_OFF / 2);
    const short8* w6p8 = reinterpret_cast<const short8*>(ws_u16 + W6PACK_OFF / 2);

    // ===== Layer 0: x(hi+lo) @ W0(hi+lo), 3-term bf16 split, relu =====
    const int rt = yb * 2 + rtl;
    f32x16 acc0, acc1;
#pragma unroll
    for (int i = 0; i < 16; ++i) { acc0[i] = 0.f; acc1[i] = 0.f; }

    const short8* xA = xp8 + (size_t)rt * 49 * 128 + lane;              // kc stride 128
    const short8* wB = w0p8 + ((size_t)n * 49 * 4 + ct0) * 128 + lane;  // kc stride 512

    short8 Ah = xA[0], Al = xA[64];
    short8 Bh0 = wB[0], Bl0 = wB[64], Bh1 = wB[128], Bl1 = wB[192];
    for (int kc = 0; kc < 49; ++kc) {
        short8 nAh, nAl, nBh0, nBl0, nBh1, nBl1;
        if (kc < 48) {
            const short8* xn = xA + (size_t)(kc + 1) * 128;
            const short8* wn = wB + (size_t)(kc + 1) * 512;
            nAh = xn[0]; nAl = xn[64];
            nBh0 = wn[0]; nBl0 = wn[64]; nBh1 = wn[128]; nBl1 = wn[192];
        }
        acc0 = MFMA32(Ah, Bh0, acc0);
        acc0 = MFMA32(Ah, Bl0, acc0);
        acc0 = MFMA32(Al, Bh0, acc0);
        acc1 = MFMA32(Ah, Bh1, acc1);
        acc1 = MFMA32(Ah, Bl1, acc1);
        acc1 = MFMA32(Al, Bh1, acc1);
        if (kc < 48) { Ah = nAh; Al = nAl; Bh0 = nBh0; Bl0 = nBl0; Bh1 = nBh1; Bl1 = nBl1; }
    }
    {
        float b0a = B0[n * 128 + ct0 * 32 + cl];
        float b0b = B0[n * 128 + (ct0 + 1) * 32 + cl];
#pragma unroll
        for (int r2 = 0; r2 < 16; ++r2) {
            int row = rtl * 32 + (r2 & 3) + 8 * (r2 >> 2) + 4 * hf;
            HsAu[(ct0 * 32 + cl) * 65 + row]       = split_pack(fmaxf(acc0[r2] + b0a, 0.f));
            HsAu[((ct0 + 1) * 32 + cl) * 65 + row] = split_pack(fmaxf(acc1[r2] + b0b, 0.f));
        }
    }
    __syncthreads();

    // ===== Layer 1: h0 @ W1 -> h1[64][65] fp32, relu (MFMA) =====
    {
        const int ctl = w & 1;
        short8 a_hi[8], a_lo[8];
        const int r32 = rtl * 32 + cl;
#pragma unroll
        for (int kc = 0; kc < 8; ++kc) {
            int kb = kc * 16 + 8 * hf;
            short8 H, L;
#pragma unroll
            for (int j = 0; j < 8; ++j) {
                unsigned u = HsAu[(kb + j) * 65 + r32];
                H[j] = (short)(u & 0xFFFFu);
                L[j] = (short)(u >> 16);
            }
            a_hi[kc] = H; a_lo[kc] = L;
        }
        f32x16 acc;
#pragma unroll
        for (int i = 0; i < 16; ++i) acc[i] = 0.f;
        const short8* wb = w1p8 + ((size_t)n * 16 + ctl) * 128 + lane;
#pragma unroll
        for (int kc = 0; kc < 8; ++kc) {
            const short8* bp = wb + (size_t)kc * 256;
            short8 Bh = bp[0], Bl = bp[64];
            acc = MFMA32(a_hi[kc], Bh, acc);
            acc = MFMA32(a_hi[kc], Bl, acc);
            acc = MFMA32(a_lo[kc], Bh, acc);
        }
        __syncthreads();
        float bias = B1[n * 64 + ctl * 32 + cl];
#pragma unroll
        for (int r2 = 0; r2 < 16; ++r2) {
            int row = rtl * 32 + (r2 & 3) + 8 * (r2 >> 2) + 4 * hf;
            HsB[(ctl * 32 + cl) * 65 + row] = fmaxf(acc[r2] + bias, 0.f);
        }
    }
    __syncthreads();

    // ===== Layers 2..5 (fp32 VALU, LDS ping-pong) =====
    midlayer< 64, 12,  3, true >(W2, B2, HsB, HsA, n, w, lane);  // h1(B)->h2(A)
    midlayer< 12,  3,  1, false>(W3, B3, HsA, HsB, n, w, lane);  // h2(A)->h3(B)
    midlayer<  3, 12,  3, true >(W4, B4, HsB, HsA, n, w, lane);  // h3(B)->h4(A)
    midlayer< 12, 64, 16, true >(W5, B5, HsA, HsB, n, w, lane);  // h4(A)->h5(B)

    // ===== Layer 6: h5 @ W6 -> h6 (packed u32), relu (MFMA) =====
    {
        short8 a_hi[4], a_lo[4];
        const int r32 = rtl * 32 + cl;
#pragma unroll
        for (int kc = 0; kc < 4; ++kc) {
            int kb = kc * 16 + 8 * hf;
            short8 H, L;
#pragma unroll
            for (int j = 0; j < 8; ++j) {
                float v = HsB[(kb + j) * 65 + r32];
                unsigned short h = bf16_rne(v);
                H[j] = (short)h;
                L[j] = (short)bf16_rne(v - bf16_to_f(h));
            }
            a_hi[kc] = H; a_lo[kc] = L;
        }
        f32x16 acc0b, acc1b;
#pragma unroll
        for (int i = 0; i < 16; ++i) { acc0b[i] = 0.f; acc1b[i] = 0.f; }
        const short8* wb = w6p8 + ((size_t)n * 16 + ct0) * 128 + lane;
#pragma unroll
        for (int kc = 0; kc < 4; ++kc) {
            const short8* bp = wb + (size_t)kc * 512;
            short8 Bh0 = bp[0],   Bl0 = bp[64];
            short8 Bh1 = bp[128], Bl1 = bp[192];
            acc0b = MFMA32(a_hi[kc], Bh0, acc0b);
            acc0b = MFMA32(a_hi[kc], Bl0, acc0b);
            acc0b = MFMA32(a_lo[kc], Bh0, acc0b);
            acc1b = MFMA32(a_hi[kc], Bh1, acc1b);
            acc1b = MFMA32(a_hi[kc], Bl1, acc1b);
            acc1b = MFMA32(a_lo[kc], Bh1, acc1b);
        }
        __syncthreads();   // h5 reads done before HsA h6-write (HsA holds h4; dead)
        float b6a = B6[n * 128 + ct0 * 32 + cl];
        float b6b = B6[n * 128 + (ct0 + 1) * 32 + cl];
#pragma unroll
        for (int r2 = 0; r2 < 16; ++r2) {
            int row = rtl * 32 + (r2 & 3) + 8 * (r2 >> 2) + 4 * hf;
            HsAu[(ct0 * 32 + cl) * 65 + row]       = split_pack(fmaxf(acc0b[r2] + b6a, 0.f));
            HsAu[((ct0 + 1) * 32 + cl) * 65 + row] = split_pack(fmaxf(acc1b[r2] + b6b, 0.f));
        }
    }
    __syncthreads();

    // ===== Layer 7: h6 @ W7, tanh, row-sum =====
    short8 a_hi[8], a_lo[8];
    {
        const int r32 = rtl * 32 + cl;
#pragma unroll
        for (int kc = 0; kc < 8; ++kc) {
            int kb = kc * 16 + 8 * hf;
            short8 H, L;
#pragma unroll
            for (int j = 0; j < 8; ++j) {
                unsigned u = HsAu[(kb + j) * 65 + r32];
                H[j] = (short)(u & 0xFFFFu);
                L[j] = (short)(u >> 16);
            }
            a_hi[kc] = H; a_lo[kc] = L;
        }
    }

    float rowsum[16];
#pragma unroll
    for (int i = 0; i < 16; ++i) rowsum[i] = 0.f;

    const short8* w7b = w7p8 + (size_t)n * 8 * 25 * 128 + lane;
    const int ctS = (w & 1) ? 13 : 0;
    const int ctE = (w & 1) ? 25 : 13;
    for (int ct = ctS; ct < ctE; ++ct) {
        // dual accumulator chains: halves serial MFMA dependency depth
        f32x16 accA, accB;
#pragma unroll
        for (int i = 0; i < 16; ++i) { accA[i] = 0.f; accB[i] = 0.f; }
#pragma unroll
        for (int kc = 0; kc < 8; ++kc) {
            const short8* bp = w7b + (size_t)(kc * 25 + ct) * 128;
            short8 Bh = bp[0], Bl = bp[64];
            accA = MFMA32(a_hi[kc], Bh, accA);
            accB = MFMA32(a_hi[kc], Bl, accB);
            accA = MFMA32(a_lo[kc], Bh, accA);
        }
        int col = ct * 32 + cl;
        if (col < 784) {
            float bias = B7[n * 784 + col];
#pragma unroll
            for (int r2 = 0; r2 < 16; ++r2)
                rowsum[r2] += fast_tanh(accA[r2] + accB[r2] + bias);
        }
    }

#pragma unroll
    for (int r2 = 0; r2 < 16; ++r2) {
        float s = rowsum[r2];
        s += __shfl_xor(s, 1);  s += __shfl_xor(s, 2);  s += __shfl_xor(s, 4);
        s += __shfl_xor(s, 8);  s += __shfl_xor(s, 16);
        rowsum[r2] = s;
    }

    float* Ps = HsB;   // dead
    Ps[t] = 0.f;       // REQUIRED: each wave writes only 32 of its 64 slots below
    __syncthreads();
    if (cl == 0) {
#pragma unroll
        for (int r2 = 0; r2 < 16; ++r2) {
            int row = rtl * 32 + (r2 & 3) + 8 * (r2 >> 2) + 4 * hf;
            Ps[w * 64 + row] = rowsum[r2];
        }
    }
    __syncthreads();
    if (t < 64) {
        float s = Ps[t] + Ps[64 + t] + Ps[128 + t] + Ps[192 + t];
        out[(size_t)(yb * 64 + t) * 10 + n] = s;
    }
}

// ---------------- fp32 fallback if ws too small ----------------
__global__ __launch_bounds__(256)
void fused_ae_fp32_kernel(const float* __restrict__ x,
                          const float* __restrict__ W0, const float* __restrict__ B0,
                          const float* __restrict__ W1, const float* __restrict__ B1,
                          const float* __restrict__ W2, const float* __restrict__ B2,
                          const float* __restrict__ W3, const float* __restrict__ B3,
                          const float* __restrict__ W4, const float* __restrict__ B4,
                          const float* __restrict__ W5, const float* __restrict__ B5,
                          const float* __restrict__ W6, const float* __restrict__ B6,
                          const float* __restrict__ W7, const float* __restrict__ B7,
                          float* __restrict__ out) {
    __shared__ float HsA[128 * 65];
    __shared__ float HsB[64 * 65];
    const int t    = threadIdx.x;
    const int lane = t & 63;
    const int w    = __builtin_amdgcn_readfirstlane(t >> 6);
    const int n    = blockIdx.x;
    const int rowbase = blockIdx.y * 64;

    float acc0[32];
#pragma unroll
    for (int j = 0; j < 32; ++j) acc0[j] = 0.f;
    float* As = HsB;
    const int r   = t >> 2;
    const int kk4 = (t & 3) * 4;
    const float* xrow = x + (size_t)(rowbase + r) * 784;
    for (int kc = 0; kc < 49; ++kc) {
        float4 xv = *(const float4*)(xrow + kc * 16 + kk4);
        As[(kk4 + 0) * 65 + r] = xv.x;
        As[(kk4 + 1) * 65 + r] = xv.y;
        As[(kk4 + 2) * 65 + r] = xv.z;
        As[(kk4 + 3) * 65 + r] = xv.w;
        __syncthreads();
        const float* W0base = W0 + ((size_t)n * 784 + (size_t)kc * 16) * 128 + w * 32;
#pragma unroll
        for (int k = 0; k < 16; ++k) {
            float a = As[k * 65 + lane];
            const float* Wk = W0base + k * 128;
#pragma unroll
            for (int j = 0; j < 32; ++j) acc0[j] = fmaf(a, Wk[j], acc0[j]);
        }
        __syncthreads();
    }
    {
        const float* bb = B0 + n * 128 + w * 32;
#pragma unroll
        for (int j = 0; j < 32; ++j)
            HsA[(w * 32 + j) * 65 + lane] = fmaxf(acc0[j] + bb[j], 0.f);
    }
    __syncthreads();

    midlayer<128, 64, 16, true >(W1, B1, HsA, HsB, n, w, lane);
    midlayer< 64, 12,  3, true >(W2, B2, HsB, HsA, n, w, lane);
    midlayer< 12,  3,  1, false>(W3, B3, HsA, HsB, n, w, lane);
    midlayer<  3, 12,  3, true >(W4, B4, HsB, HsA, n, w, lane);
    midlayer< 12, 64, 16, true >(W5, B5, HsA, HsB, n, w, lane);
    midlayer< 64,128, 32, true >(W6, B6, HsB, HsA, n, w, lane);

    float lane_sum = 0.f;
    const int j0w = w * 196;
    for (int c = 0; c < 7; ++c) {
        const int j0 = j0w + c * 28;
        float acc[28];
        const float* bb = B7 + n * 784 + j0;
#pragma unroll
        for (int j = 0; j < 28; ++j) acc[j] = bb[j];
        for (int k = 0; k < 128; ++k) {
            float a = HsA[k * 65 + lane];
            const float* Wk = W7 + ((size_t)n * 128 + k) * 784 + j0;
#pragma unroll
            for (int j = 0; j < 28; ++j) acc[j] = fmaf(a, Wk[j], acc[j]);
        }
#pragma unroll
        for (int j = 0; j < 28; ++j) lane_sum += fast_tanh(acc[j]);
    }
    float* partial = HsB;
    partial[w * 64 + lane] = lane_sum;
    __syncthreads();
    if (t < 64) {
        float s = partial[t] + partial[64 + t] + partial[128 + t] + partial[192 + t];
        out[(size_t)(rowbase + t) * 10 + n] = s;
    }
}

extern "C" void kernel_launch(void* const* d_in, const int* in_sizes, int n_in,
                              void* d_out, int out_size, void* d_ws, size_t ws_size,
                              hipStream_t stream) {
    (void)in_sizes; (void)n_in; (void)out_size;
    const float* x  = (const float*)d_in[0];
    const float* W0 = (const float*)d_in[1];  const float* B0 = (const float*)d_in[2];
    const float* W1 = (const float*)d_in[3];  const float* B1 = (const float*)d_in[4];
    const float* W2 = (const float*)d_in[5];  const float* B2 = (const float*)d_in[6];
    const float* W3 = (const float*)d_in[7];  const float* B3 = (const float*)d_in[8];
    const float* W4 = (const float*)d_in[9];  const float* B4 = (const float*)d_in[10];
    const float* W5 = (const float*)d_in[11]; const float* B5 = (const float*)d_in[12];
    const float* W6 = (const float*)d_in[13]; const float* B6 = (const float*)d_in[14];
    const float* W7 = (const float*)d_in[15]; const float* B7 = (const float*)d_in[16];
    float* out = (float*)d_out;

    if (ws_size >= TOTAL_WS) {
        unsigned short* ws_u16 = (unsigned short*)d_ws;
        hipLaunchKernelGGL(pack_all_kernel, dim3(PACK_GRID), dim3(256), 0, stream,
                           x, W0, W1, W6, W7, ws_u16);
        hipLaunchKernelGGL(fused_ae_mfma_kernel, dim3(NNETS * (BATCH / 64)), dim3(256), 0, stream,
                           B0, B1, W2, B2, W3, B3, W4, B4, W5, B5, B6, B7, ws_u16, out);
    } else {
        hipLaunchKernelGGL(fused_ae_fp32_kernel, dim3(NNETS, BATCH / 64), dim3(256), 0, stream,
                           x, W0, B0, W1, B1, W2, B2, W3, B3,
                           W4, B4, W5, B5, W6, B6, W7, B7, out);
    }
}

// Round 10
// 262.160 us; speedup vs baseline: 1.0592x; 1.0586x over previous
//
#include <hip/hip_runtime.h>

#define NNETS 10
#define BATCH 8192

typedef __attribute__((ext_vector_type(8)))  short  short8;
typedef __attribute__((ext_vector_type(16))) float  f32x16;

// ---------------- workspace layout (bytes) ----------------
// xpack : [rt(256)][kc(49)][hl(2)][lane(64)][j(8)] bf16
// w0pack: [n(10)][kc(49)][ct(4)][hl(2)][lane(64)][j(8)]
// w7pack: [n(10)][kc(8)][ct(25)][hl(2)][lane(64)][j(8)]
// w1pack: [n(10)][kc(8)][ct(2)][hl(2)][lane(64)][j(8)]
// w6pack: [n(10)][kc(4)][ct(4)][hl(2)][lane(64)][j(8)]
#define XPACK_BYTES  (256UL*49*2*64*8*2)
#define W0PACK_OFF   (XPACK_BYTES)
#define W0PACK_BYTES (10UL*49*4*2*64*8*2)
#define W7PACK_OFF   (W0PACK_OFF + W0PACK_BYTES)
#define W7PACK_BYTES (10UL*8*25*2*64*8*2)
#define W1PACK_OFF   (W7PACK_OFF + W7PACK_BYTES)
#define W1PACK_BYTES (10UL*8*2*2*64*8*2)
#define W6PACK_OFF   (W1PACK_OFF + W1PACK_BYTES)
#define W6PACK_BYTES (10UL*4*4*2*64*8*2)
#define TOTAL_WS     (W6PACK_OFF + W6PACK_BYTES)

// pack grid ranges (blocks of 256)
#define PX_BLOCKS  (256 * 7)
#define PW0_BLOCKS 490
#define PW7_BLOCKS 500
#define PW1_BLOCKS 40
#define PW6_BLOCKS 40
#define PACK_GRID  (PX_BLOCKS + PW0_BLOCKS + PW7_BLOCKS + PW1_BLOCKS + PW6_BLOCKS)

// ---------------- helpers ----------------
__device__ __forceinline__ float fast_tanh(float x) {
    float e = __expf(2.f * x);
    return 1.f - 2.f * __builtin_amdgcn_rcpf(1.f + e);
}
__device__ __forceinline__ unsigned short bf16_rne(float v) {
    unsigned u = __float_as_uint(v);
    unsigned r = (u + 0x7FFFu + ((u >> 16) & 1u)) >> 16;
    return (unsigned short)r;
}
__device__ __forceinline__ float bf16_to_f(unsigned short h) {
    return __uint_as_float(((unsigned)h) << 16);
}
__device__ __forceinline__ unsigned split_pack(float v) {
    unsigned short h = bf16_rne(v);
    unsigned short l = bf16_rne(v - bf16_to_f(h));
    return (unsigned)h | ((unsigned)l << 16);
}

// ---------------- merged pack kernel (unchanged from r9) ----------------
__device__ __forceinline__ void pack_x_body(int blk, int t, const float* __restrict__ x,
                                            unsigned short* __restrict__ xp,
                                            float (*xs)[113]) {
    const int rt = blk / 7;
    const int c  = blk - rt * 7;
#pragma unroll
    for (int it = 0; it < 4; ++it) {
        int f = t + 256 * it;
        if (f < 896) {
            int row  = f / 28;
            int colq = f - row * 28;
            float4 v = *(const float4*)(x + (size_t)(rt * 32 + row) * 784 + c * 112 + colq * 4);
            xs[row][colq * 4 + 0] = v.x;
            xs[row][colq * 4 + 1] = v.y;
            xs[row][colq * 4 + 2] = v.z;
            xs[row][colq * 4 + 3] = v.w;
        }
    }
    __syncthreads();
    const int lane = t & 63;
    const int sub  = t >> 6;
    const int srow = lane & 31;
    const int skb  = 8 * (lane >> 5);
    for (int idx = sub; idx < 14; idx += 4) {
        int kcl = idx >> 1;
        int hl  = idx & 1;
        short8 V;
#pragma unroll
        for (int j = 0; j < 8; ++j) {
            float v = xs[srow][kcl * 16 + skb + j];
            unsigned short h = bf16_rne(v);
            if (hl == 0) V[j] = (short)h;
            else         V[j] = (short)bf16_rne(v - bf16_to_f(h));
        }
        int kc_global = c * 7 + kcl;
        short8* dst = reinterpret_cast<short8*>(xp) + (size_t)(rt * 49 + kc_global) * 128 + hl * 64 + lane;
        *dst = V;
    }
}

__device__ __forceinline__ void pack_w0_body(int tid, const float* __restrict__ W0,
                                             unsigned short* __restrict__ wp) {
    if (tid >= 10 * 49 * 4 * 64) return;
    int lane = tid & 63; int t2 = tid >> 6;
    int ct = t2 % 4;  t2 /= 4;
    int kc = t2 % 49; int n = t2 / 49;
    int col = ct * 32 + (lane & 31);
    int kb  = kc * 16 + 8 * (lane >> 5);
    short8 H, L;
#pragma unroll
    for (int j = 0; j < 8; ++j) {
        float v = W0[((size_t)n * 784 + kb + j) * 128 + col];
        unsigned short h = bf16_rne(v);
        H[j] = (short)h;
        L[j] = (short)bf16_rne(v - bf16_to_f(h));
    }
    short8* dst = reinterpret_cast<short8*>(wp + (size_t)((n * 49 + kc) * 4 + ct) * 1024) + lane;
    dst[0]  = H;
    dst[64] = L;
}

__device__ __forceinline__ void pack_w7_body(int tid, const float* __restrict__ W7,
                                             unsigned short* __restrict__ wp) {
    if (tid >= 10 * 8 * 25 * 64) return;
    int lane = tid & 63; int t2 = tid >> 6;
    int ct = t2 % 25; t2 /= 25;
    int kc = t2 % 8;  int n = t2 / 8;
    int col = ct * 32 + (lane & 31);
    int kb  = kc * 16 + 8 * (lane >> 5);
    short8 H, L;
#pragma unroll
    for (int j = 0; j < 8; ++j) {
        float v = (col < 784) ? W7[((size_t)n * 128 + kb + j) * 784 + col] : 0.f;
        unsigned short h = bf16_rne(v);
        H[j] = (short)h;
        L[j] = (short)bf16_rne(v - bf16_to_f(h));
    }
    short8* dst = reinterpret_cast<short8*>(wp + (size_t)((n * 8 + kc) * 25 + ct) * 1024) + lane;
    dst[0]  = H;
    dst[64] = L;
}

__device__ __forceinline__ void pack_w1_body(int tid, const float* __restrict__ W1,
                                             unsigned short* __restrict__ wp) {
    if (tid >= 10 * 8 * 2 * 64) return;
    int lane = tid & 63; int t2 = tid >> 6;
    int ct = t2 % 2; t2 /= 2;
    int kc = t2 % 8; int n = t2 / 8;
    int col = ct * 32 + (lane & 31);
    int kb  = kc * 16 + 8 * (lane >> 5);
    short8 H, L;
#pragma unroll
    for (int j = 0; j < 8; ++j) {
        float v = W1[((size_t)n * 128 + kb + j) * 64 + col];
        unsigned short h = bf16_rne(v);
        H[j] = (short)h;
        L[j] = (short)bf16_rne(v - bf16_to_f(h));
    }
    short8* dst = reinterpret_cast<short8*>(wp + (size_t)((n * 8 + kc) * 2 + ct) * 1024) + lane;
    dst[0]  = H;
    dst[64] = L;
}

__device__ __forceinline__ void pack_w6_body(int tid, const float* __restrict__ W6,
                                             unsigned short* __restrict__ wp) {
    if (tid >= 10 * 4 * 4 * 64) return;
    int lane = tid & 63; int t2 = tid >> 6;
    int ct = t2 % 4; t2 /= 4;
    int kc = t2 % 4; int n = t2 / 4;
    int col = ct * 32 + (lane & 31);
    int kb  = kc * 16 + 8 * (lane >> 5);
    short8 H, L;
#pragma unroll
    for (int j = 0; j < 8; ++j) {
        float v = W6[((size_t)n * 64 + kb + j) * 128 + col];
        unsigned short h = bf16_rne(v);
        H[j] = (short)h;
        L[j] = (short)bf16_rne(v - bf16_to_f(h));
    }
    short8* dst = reinterpret_cast<short8*>(wp + (size_t)((n * 4 + kc) * 4 + ct) * 1024) + lane;
    dst[0]  = H;
    dst[64] = L;
}

__global__ __launch_bounds__(256)
void pack_all_kernel(const float* __restrict__ x,
                     const float* __restrict__ W0, const float* __restrict__ W1,
                     const float* __restrict__ W6, const float* __restrict__ W7,
                     unsigned short* __restrict__ ws_u16) {
    __shared__ float xs[32][113];
    int b = blockIdx.x;
    if (b < PX_BLOCKS) {
        pack_x_body(b, threadIdx.x, x, ws_u16, xs);
    } else if (b < PX_BLOCKS + PW0_BLOCKS) {
        pack_w0_body((b - PX_BLOCKS) * 256 + threadIdx.x, W0, ws_u16 + W0PACK_OFF / 2);
    } else if (b < PX_BLOCKS + PW0_BLOCKS + PW7_BLOCKS) {
        pack_w7_body((b - PX_BLOCKS - PW0_BLOCKS) * 256 + threadIdx.x, W7, ws_u16 + W7PACK_OFF / 2);
    } else if (b < PX_BLOCKS + PW0_BLOCKS + PW7_BLOCKS + PW1_BLOCKS) {
        pack_w1_body((b - PX_BLOCKS - PW0_BLOCKS - PW7_BLOCKS) * 256 + threadIdx.x, W1, ws_u16 + W1PACK_OFF / 2);
    } else {
        pack_w6_body((b - PX_BLOCKS - PW0_BLOCKS - PW7_BLOCKS - PW1_BLOCKS) * 256 + threadIdx.x, W6, ws_u16 + W6PACK_OFF / 2);
    }
}

// ---------------- mid layers (fp32 VALU; r4-proven wave-split) ----------
template<int ID, int OD, int NO, bool RELU>
__device__ __forceinline__ void midlayer(const float* __restrict__ W,
                                         const float* __restrict__ bias,
                                         const float* bufIn, float* bufOut,
                                         int n, int w, int lane) {
    const int o0 = w * NO;
    if (o0 < OD) {
        float acc[NO];
#pragma unroll
        for (int j = 0; j < NO; ++j) acc[j] = bias[n * OD + o0 + j];
        for (int k = 0; k < ID; ++k) {
            float a = bufIn[k * 65 + lane];
            const float* Wk = W + ((size_t)n * ID + k) * OD + o0;
#pragma unroll
            for (int j = 0; j < NO; ++j) acc[j] = fmaf(a, Wk[j], acc[j]);
        }
#pragma unroll
        for (int j = 0; j < NO; ++j) {
            float v = acc[j];
            if (RELU) v = fmaxf(v, 0.f);
            bufOut[(o0 + j) * 65 + lane] = v;
        }
    }
    __syncthreads();
}

#define MFMA32(A, B, C) __builtin_amdgcn_mfma_f32_32x32x16_bf16(A, B, C, 0, 0, 0)

// ---------------- main fused kernel ----------------
// SINGLE 33.3 KB LDS buffer -> 4 blocks/CU (was 50 KB -> 3). Region plan
// (feats = first index of Hs[feat*65+row]):
//   h0: u32 feats 0-127  | h1: f32 feats 0-63 (after L1 internal barrier)
//   h2: feats 64-75 | h3: 76-78 | h4: 79-90 | h5: feats 0-63 (h1 dead)
//   h6: u32 feats 0-127 (after L6 internal barrier) | partials (after L7 barrier)
// Ledger: r4 structure proven; landmines: (256,4) bound -> spill (r5);
// register midlayers (r6); raw-x L0 (r8). Keep: packed x hi+lo 6-MFMA L0,
// wave-split mids, rcp-tanh, dual-chain L7, XCD swizzle.
__global__ __launch_bounds__(256)
void fused_ae_mfma_kernel(const float* __restrict__ B0,
                          const float* __restrict__ B1,
                          const float* __restrict__ W2, const float* __restrict__ B2,
                          const float* __restrict__ W3, const float* __restrict__ B3,
                          const float* __restrict__ W4, const float* __restrict__ B4,
                          const float* __restrict__ W5, const float* __restrict__ B5,
                          const float* __restrict__ B6,
                          const float* __restrict__ B7,
                          const unsigned short* __restrict__ ws_u16,
                          float* __restrict__ out) {
    __shared__ float Hs[128 * 65];    // 33.3 KB single buffer
    unsigned* Hsu = reinterpret_cast<unsigned*>(Hs);

    const int t    = threadIdx.x;
    const int lane = t & 63;
    const int w    = __builtin_amdgcn_readfirstlane(t >> 6);  // wave 0..3

    // XCD swizzle: all 10 nets sharing a y-tile land on the same XCD.
    const int bid = blockIdx.x;
    const int g   = bid & 7;
    const int j8  = bid >> 3;          // 0..159
    const int yb  = (g << 4) + (j8 / 10);
    const int n   = j8 % 10;

    const int cl   = lane & 31;
    const int hf   = lane >> 5;
    const int rtl  = w >> 1;
    const int ct0  = (w & 1) * 2;

    const short8* xp8  = reinterpret_cast<const short8*>(ws_u16);
    const short8* w0p8 = reinterpret_cast<const short8*>(ws_u16 + W0PACK_OFF / 2);
    const short8* w7p8 = reinterpret_cast<const short8*>(ws_u16 + W7PACK_OFF / 2);
    const short8* w1p8 = reinterpret_cast<const short8*>(ws_u16 + W1PACK_OFF / 2);
    const short8* w6p8 = reinterpret_cast<const short8*>(ws_u16 + W6PACK_OFF / 2);

    // ===== Layer 0: x(hi+lo) @ W0(hi+lo), 3-term bf16 split, relu =====
    const int rt = yb * 2 + rtl;
    f32x16 acc0, acc1;
#pragma unroll
    for (int i = 0; i < 16; ++i) { acc0[i] = 0.f; acc1[i] = 0.f; }

    const short8* xA = xp8 + (size_t)rt * 49 * 128 + lane;
    const short8* wB = w0p8 + ((size_t)n * 49 * 4 + ct0) * 128 + lane;

    short8 Ah = xA[0], Al = xA[64];
    short8 Bh0 = wB[0], Bl0 = wB[64], Bh1 = wB[128], Bl1 = wB[192];
    for (int kc = 0; kc < 49; ++kc) {
        short8 nAh, nAl, nBh0, nBl0, nBh1, nBl1;
        if (kc < 48) {
            const short8* xn = xA + (size_t)(kc + 1) * 128;
            const short8* wn = wB + (size_t)(kc + 1) * 512;
            nAh = xn[0]; nAl = xn[64];
            nBh0 = wn[0]; nBl0 = wn[64]; nBh1 = wn[128]; nBl1 = wn[192];
        }
        acc0 = MFMA32(Ah, Bh0, acc0);
        acc0 = MFMA32(Ah, Bl0, acc0);
        acc0 = MFMA32(Al, Bh0, acc0);
        acc1 = MFMA32(Ah, Bh1, acc1);
        acc1 = MFMA32(Ah, Bl1, acc1);
        acc1 = MFMA32(Al, Bh1, acc1);
        if (kc < 48) { Ah = nAh; Al = nAl; Bh0 = nBh0; Bl0 = nBl0; Bh1 = nBh1; Bl1 = nBl1; }
    }
    {
        float b0a = B0[n * 128 + ct0 * 32 + cl];
        float b0b = B0[n * 128 + (ct0 + 1) * 32 + cl];
#pragma unroll
        for (int r2 = 0; r2 < 16; ++r2) {
            int row = rtl * 32 + (r2 & 3) + 8 * (r2 >> 2) + 4 * hf;
            Hsu[(ct0 * 32 + cl) * 65 + row]       = split_pack(fmaxf(acc0[r2] + b0a, 0.f));
            Hsu[((ct0 + 1) * 32 + cl) * 65 + row] = split_pack(fmaxf(acc1[r2] + b0b, 0.f));
        }
    }
    __syncthreads();

    // ===== Layer 1: h0 @ W1 -> h1 (f32, feats 0-63) over h0's region =====
    {
        const int ctl = w & 1;
        short8 a_hi[8], a_lo[8];
        const int r32 = rtl * 32 + cl;
#pragma unroll
        for (int kc = 0; kc < 8; ++kc) {
            int kb = kc * 16 + 8 * hf;
            short8 H, L;
#pragma unroll
            for (int j = 0; j < 8; ++j) {
                unsigned u = Hsu[(kb + j) * 65 + r32];
                H[j] = (short)(u & 0xFFFFu);
                L[j] = (short)(u >> 16);
            }
            a_hi[kc] = H; a_lo[kc] = L;
        }
        f32x16 acc;
#pragma unroll
        for (int i = 0; i < 16; ++i) acc[i] = 0.f;
        const short8* wb = w1p8 + ((size_t)n * 16 + ctl) * 128 + lane;
#pragma unroll
        for (int kc = 0; kc < 8; ++kc) {
            const short8* bp = wb + (size_t)kc * 256;
            short8 Bh = bp[0], Bl = bp[64];
            acc = MFMA32(a_hi[kc], Bh, acc);
            acc = MFMA32(a_hi[kc], Bl, acc);
            acc = MFMA32(a_lo[kc], Bh, acc);
        }
        __syncthreads();   // all h0 reads complete -> buffer reusable for h1
        float bias = B1[n * 64 + ctl * 32 + cl];
#pragma unroll
        for (int r2 = 0; r2 < 16; ++r2) {
            int row = rtl * 32 + (r2 & 3) + 8 * (r2 >> 2) + 4 * hf;
            Hs[(ctl * 32 + cl) * 65 + row] = fmaxf(acc[r2] + bias, 0.f);
        }
    }
    __syncthreads();

    // ===== Layers 2..5 (fp32 VALU, region-hopping within Hs) =====
    midlayer< 64, 12,  3, true >(W2, B2, Hs,           Hs + 64 * 65, n, w, lane); // h1 -> h2
    midlayer< 12,  3,  1, false>(W3, B3, Hs + 64 * 65, Hs + 76 * 65, n, w, lane); // h2 -> h3
    midlayer<  3, 12,  3, true >(W4, B4, Hs + 76 * 65, Hs + 79 * 65, n, w, lane); // h3 -> h4
    midlayer< 12, 64, 16, true >(W5, B5, Hs + 79 * 65, Hs,           n, w, lane); // h4 -> h5 (h1 dead)

    // ===== Layer 6: h5 @ W6 -> h6 (u32, feats 0-127) over whole buffer =====
    {
        short8 a_hi[4], a_lo[4];
        const int r32 = rtl * 32 + cl;
#pragma unroll
        for (int kc = 0; kc < 4; ++kc) {
            int kb = kc * 16 + 8 * hf;
            short8 H, L;
#pragma unroll
            for (int j = 0; j < 8; ++j) {
                float v = Hs[(kb + j) * 65 + r32];
                unsigned short h = bf16_rne(v);
                H[j] = (short)h;
                L[j] = (short)bf16_rne(v - bf16_to_f(h));
            }
            a_hi[kc] = H; a_lo[kc] = L;
        }
        f32x16 acc0b, acc1b;
#pragma unroll
        for (int i = 0; i < 16; ++i) { acc0b[i] = 0.f; acc1b[i] = 0.f; }
        const short8* wb = w6p8 + ((size_t)n * 16 + ct0) * 128 + lane;
#pragma unroll
        for (int kc = 0; kc < 4; ++kc) {
            const short8* bp = wb + (size_t)kc * 512;
            short8 Bh0 = bp[0],   Bl0 = bp[64];
            short8 Bh1 = bp[128], Bl1 = bp[192];
            acc0b = MFMA32(a_hi[kc], Bh0, acc0b);
            acc0b = MFMA32(a_hi[kc], Bl0, acc0b);
            acc0b = MFMA32(a_lo[kc], Bh0, acc0b);
            acc1b = MFMA32(a_hi[kc], Bh1, acc1b);
            acc1b = MFMA32(a_hi[kc], Bl1, acc1b);
            acc1b = MFMA32(a_lo[kc], Bh1, acc1b);
        }
        __syncthreads();   // all h5 reads complete -> buffer reusable for h6
        float b6a = B6[n * 128 + ct0 * 32 + cl];
        float b6b = B6[n * 128 + (ct0 + 1) * 32 + cl];
#pragma unroll
        for (int r2 = 0; r2 < 16; ++r2) {
            int row = rtl * 32 + (r2 & 3) + 8 * (r2 >> 2) + 4 * hf;
            Hsu[(ct0 * 32 + cl) * 65 + row]       = split_pack(fmaxf(acc0b[r2] + b6a, 0.f));
            Hsu[((ct0 + 1) * 32 + cl) * 65 + row] = split_pack(fmaxf(acc1b[r2] + b6b, 0.f));
        }
    }
    __syncthreads();

    // ===== Layer 7: h6 @ W7, tanh, row-sum =====
    short8 a_hi[8], a_lo[8];
    {
        const int r32 = rtl * 32 + cl;
#pragma unroll
        for (int kc = 0; kc < 8; ++kc) {
            int kb = kc * 16 + 8 * hf;
            short8 H, L;
#pragma unroll
            for (int j = 0; j < 8; ++j) {
                unsigned u = Hsu[(kb + j) * 65 + r32];
                H[j] = (short)(u & 0xFFFFu);
                L[j] = (short)(u >> 16);
            }
            a_hi[kc] = H; a_lo[kc] = L;
        }
    }
    __syncthreads();   // all h6 reads complete -> buffer reusable for partials

    float rowsum[16];
#pragma unroll
    for (int i = 0; i < 16; ++i) rowsum[i] = 0.f;

    const short8* w7b = w7p8 + (size_t)n * 8 * 25 * 128 + lane;
    const int ctS = (w & 1) ? 13 : 0;
    const int ctE = (w & 1) ? 25 : 13;
    for (int ct = ctS; ct < ctE; ++ct) {
        f32x16 accA, accB;   // dual chains: halves serial MFMA dependency depth
#pragma unroll
        for (int i = 0; i < 16; ++i) { accA[i] = 0.f; accB[i] = 0.f; }
#pragma unroll
        for (int kc = 0; kc < 8; ++kc) {
            const short8* bp = w7b + (size_t)(kc * 25 + ct) * 128;
            short8 Bh = bp[0], Bl = bp[64];
            accA = MFMA32(a_hi[kc], Bh, accA);
            accB = MFMA32(a_hi[kc], Bl, accB);
            accA = MFMA32(a_lo[kc], Bh, accA);
        }
        int col = ct * 32 + cl;
        if (col < 784) {
            float bias = B7[n * 784 + col];
#pragma unroll
            for (int r2 = 0; r2 < 16; ++r2)
                rowsum[r2] += fast_tanh(accA[r2] + accB[r2] + bias);
        }
    }

#pragma unroll
    for (int r2 = 0; r2 < 16; ++r2) {
        float s = rowsum[r2];
        s += __shfl_xor(s, 1);  s += __shfl_xor(s, 2);  s += __shfl_xor(s, 4);
        s += __shfl_xor(s, 8);  s += __shfl_xor(s, 16);
        rowsum[r2] = s;
    }

    float* Ps = Hs;    // safe: post-fragload barrier above guards h6 reads
    Ps[t] = 0.f;       // REQUIRED: each wave writes only 32 of its 64 slots below
    __syncthreads();
    if (cl == 0) {
#pragma unroll
        for (int r2 = 0; r2 < 16; ++r2) {
            int row = rtl * 32 + (r2 & 3) + 8 * (r2 >> 2) + 4 * hf;
            Ps[w * 64 + row] = rowsum[r2];
        }
    }
    __syncthreads();
    if (t < 64) {
        float s = Ps[t] + Ps[64 + t] + Ps[128 + t] + Ps[192 + t];
        out[(size_t)(yb * 64 + t) * 10 + n] = s;
    }
}

// ---------------- fp32 fallback if ws too small ----------------
__global__ __launch_bounds__(256)
void fused_ae_fp32_kernel(const float* __restrict__ x,
                          const float* __restrict__ W0, const float* __restrict__ B0,
                          const float* __restrict__ W1, const float* __restrict__ B1,
                          const float* __restrict__ W2, const float* __restrict__ B2,
                          const float* __restrict__ W3, const float* __restrict__ B3,
                          const float* __restrict__ W4, const float* __restrict__ B4,
                          const float* __restrict__ W5, const float* __restrict__ B5,
                          const float* __restrict__ W6, const float* __restrict__ B6,
                          const float* __restrict__ W7, const float* __restrict__ B7,
                          float* __restrict__ out) {
    __shared__ float HsA[128 * 65];
    __shared__ float HsB[64 * 65];
    const int t    = threadIdx.x;
    const int lane = t & 63;
    const int w    = __builtin_amdgcn_readfirstlane(t >> 6);
    const int n    = blockIdx.x;
    const int rowbase = blockIdx.y * 64;

    float acc0[32];
#pragma unroll
    for (int j = 0; j < 32; ++j) acc0[j] = 0.f;
    float* As = HsB;
    const int r   = t >> 2;
    const int kk4 = (t & 3) * 4;
    const float* xrow = x + (size_t)(rowbase + r) * 784;
    for (int kc = 0; kc < 49; ++kc) {
        float4 xv = *(const float4*)(xrow + kc * 16 + kk4);
        As[(kk4 + 0) * 65 + r] = xv.x;
        As[(kk4 + 1) * 65 + r] = xv.y;
        As[(kk4 + 2) * 65 + r] = xv.z;
        As[(kk4 + 3) * 65 + r] = xv.w;
        __syncthreads();
        const float* W0base = W0 + ((size_t)n * 784 + (size_t)kc * 16) * 128 + w * 32;
#pragma unroll
        for (int k = 0; k < 16; ++k) {
            float a = As[k * 65 + lane];
            const float* Wk = W0base + k * 128;
#pragma unroll
            for (int j = 0; j < 32; ++j) acc0[j] = fmaf(a, Wk[j], acc0[j]);
        }
        __syncthreads();
    }
    {
        const float* bb = B0 + n * 128 + w * 32;
#pragma unroll
        for (int j = 0; j < 32; ++j)
            HsA[(w * 32 + j) * 65 + lane] = fmaxf(acc0[j] + bb[j], 0.f);
    }
    __syncthreads();

    midlayer<128, 64, 16, true >(W1, B1, HsA, HsB, n, w, lane);
    midlayer< 64, 12,  3, true >(W2, B2, HsB, HsA, n, w, lane);
    midlayer< 12,  3,  1, false>(W3, B3, HsA, HsB, n, w, lane);
    midlayer<  3, 12,  3, true >(W4, B4, HsB, HsA, n, w, lane);
    midlayer< 12, 64, 16, true >(W5, B5, HsA, HsB, n, w, lane);
    midlayer< 64,128, 32, true >(W6, B6, HsB, HsA, n, w, lane);

    float lane_sum = 0.f;
    const int j0w = w * 196;
    for (int c = 0; c < 7; ++c) {
        const int j0 = j0w + c * 28;
        float acc[28];
        const float* bb = B7 + n * 784 + j0;
#pragma unroll
        for (int j = 0; j < 28; ++j) acc[j] = bb[j];
        for (int k = 0; k < 128; ++k) {
            float a = HsA[k * 65 + lane];
            const float* Wk = W7 + ((size_t)n * 128 + k) * 784 + j0;
#pragma unroll
            for (int j = 0; j < 28; ++j) acc[j] = fmaf(a, Wk[j], acc[j]);
        }
#pragma unroll
        for (int j = 0; j < 28; ++j) lane_sum += fast_tanh(acc[j]);
    }
    float* partial = HsB;
    partial[w * 64 + lane] = lane_sum;
    __syncthreads();
    if (t < 64) {
        float s = partial[t] + partial[64 + t] + partial[128 + t] + partial[192 + t];
        out[(size_t)(rowbase + t) * 10 + n] = s;
    }
}

extern "C" void kernel_launch(void* const* d_in, const int* in_sizes, int n_in,
                              void* d_out, int out_size, void* d_ws, size_t ws_size,
                              hipStream_t stream) {
    (void)in_sizes; (void)n_in; (void)out_size;
    const float* x  = (const float*)d_in[0];
    const float* W0 = (const float*)d_in[1];  const float* B0 = (const float*)d_in[2];
    const float* W1 = (const float*)d_in[3];  const float* B1 = (const float*)d_in[4];
    const float* W2 = (const float*)d_in[5];  const float* B2 = (const float*)d_in[6];
    const float* W3 = (const float*)d_in[7];  const float* B3 = (const float*)d_in[8];
    const float* W4 = (const float*)d_in[9];  const float* B4 = (const float*)d_in[10];
    const float* W5 = (const float*)d_in[11]; const float* B5 = (const float*)d_in[12];
    const float* W6 = (const float*)d_in[13]; const float* B6 = (const float*)d_in[14];
    const float* W7 = (const float*)d_in[15]; const float* B7 = (const float*)d_in[16];
    float* out = (float*)d_out;

    if (ws_size >= TOTAL_WS) {
        unsigned short* ws_u16 = (unsigned short*)d_ws;
        hipLaunchKernelGGL(pack_all_kernel, dim3(PACK_GRID), dim3(256), 0, stream,
                           x, W0, W1, W6, W7, ws_u16);
        hipLaunchKernelGGL(fused_ae_mfma_kernel, dim3(NNETS * (BATCH / 64)), dim3(256), 0, stream,
                           B0, B1, W2, B2, W3, B3, W4, B4, W5, B5, B6, B7, ws_u16, out);
    } else {
        hipLaunchKernelGGL(fused_ae_fp32_kernel, dim3(NNETS, BATCH / 64), dim3(256), 0, stream,
                           x, W0, B0, W1, B1, W2, B2, W3, B3,
                           W4, B4, W5, B5, W6, B6, W7, B7, out);
    }
}

// Round 11
// 257.656 us; speedup vs baseline: 1.0777x; 1.0175x over previous
//
#include <hip/hip_runtime.h>

#define NNETS 10
#define BATCH 8192

typedef __attribute__((ext_vector_type(8)))  short  short8;
typedef __attribute__((ext_vector_type(16))) float  f32x16;

// ---------------- workspace layout (bytes) ----------------
// xpack : [rt(256)][kc(49)][hl(2)][lane(64)][j(8)] bf16
// w0pack: [n(10)][kc(49)][ct(4)][hl(2)][lane(64)][j(8)]
// w7pack: [n(10)][kc(8)][ct(25)][lane(64)][j(8)]   <-- HI ONLY (r11: lo dropped)
// w1pack: [n(10)][kc(8)][ct(2)][hl(2)][lane(64)][j(8)]
// w6pack: [n(10)][kc(4)][ct(4)][hl(2)][lane(64)][j(8)]
#define XPACK_BYTES  (256UL*49*2*64*8*2)
#define W0PACK_OFF   (XPACK_BYTES)
#define W0PACK_BYTES (10UL*49*4*2*64*8*2)
#define W7PACK_OFF   (W0PACK_OFF + W0PACK_BYTES)
#define W7PACK_BYTES (10UL*8*25*64*8*2)
#define W1PACK_OFF   (W7PACK_OFF + W7PACK_BYTES)
#define W1PACK_BYTES (10UL*8*2*2*64*8*2)
#define W6PACK_OFF   (W1PACK_OFF + W1PACK_BYTES)
#define W6PACK_BYTES (10UL*4*4*2*64*8*2)
#define TOTAL_WS     (W6PACK_OFF + W6PACK_BYTES)

// pack grid ranges (blocks of 256)
#define PX_BLOCKS  (256 * 7)
#define PW0_BLOCKS 490
#define PW7_BLOCKS 500
#define PW1_BLOCKS 40
#define PW6_BLOCKS 40
#define PACK_GRID  (PX_BLOCKS + PW0_BLOCKS + PW7_BLOCKS + PW1_BLOCKS + PW6_BLOCKS)

// ---------------- helpers ----------------
__device__ __forceinline__ float fast_tanh(float x) {
    float e = __expf(2.f * x);
    return 1.f - 2.f * __builtin_amdgcn_rcpf(1.f + e);
}
__device__ __forceinline__ unsigned short bf16_rne(float v) {
    unsigned u = __float_as_uint(v);
    unsigned r = (u + 0x7FFFu + ((u >> 16) & 1u)) >> 16;
    return (unsigned short)r;
}
__device__ __forceinline__ float bf16_to_f(unsigned short h) {
    return __uint_as_float(((unsigned)h) << 16);
}
__device__ __forceinline__ unsigned split_pack(float v) {
    unsigned short h = bf16_rne(v);
    unsigned short l = bf16_rne(v - bf16_to_f(h));
    return (unsigned)h | ((unsigned)l << 16);
}

// ---------------- merged pack kernel ----------------
__device__ __forceinline__ void pack_x_body(int blk, int t, const float* __restrict__ x,
                                            unsigned short* __restrict__ xp,
                                            float (*xs)[113]) {
    const int rt = blk / 7;
    const int c  = blk - rt * 7;
#pragma unroll
    for (int it = 0; it < 4; ++it) {
        int f = t + 256 * it;
        if (f < 896) {
            int row  = f / 28;
            int colq = f - row * 28;
            float4 v = *(const float4*)(x + (size_t)(rt * 32 + row) * 784 + c * 112 + colq * 4);
            xs[row][colq * 4 + 0] = v.x;
            xs[row][colq * 4 + 1] = v.y;
            xs[row][colq * 4 + 2] = v.z;
            xs[row][colq * 4 + 3] = v.w;
        }
    }
    __syncthreads();
    const int lane = t & 63;
    const int sub  = t >> 6;
    const int srow = lane & 31;
    const int skb  = 8 * (lane >> 5);
    for (int idx = sub; idx < 14; idx += 4) {
        int kcl = idx >> 1;
        int hl  = idx & 1;
        short8 V;
#pragma unroll
        for (int j = 0; j < 8; ++j) {
            float v = xs[srow][kcl * 16 + skb + j];
            unsigned short h = bf16_rne(v);
            if (hl == 0) V[j] = (short)h;
            else         V[j] = (short)bf16_rne(v - bf16_to_f(h));
        }
        int kc_global = c * 7 + kcl;
        short8* dst = reinterpret_cast<short8*>(xp) + (size_t)(rt * 49 + kc_global) * 128 + hl * 64 + lane;
        *dst = V;
    }
}

__device__ __forceinline__ void pack_w0_body(int tid, const float* __restrict__ W0,
                                             unsigned short* __restrict__ wp) {
    if (tid >= 10 * 49 * 4 * 64) return;
    int lane = tid & 63; int t2 = tid >> 6;
    int ct = t2 % 4;  t2 /= 4;
    int kc = t2 % 49; int n = t2 / 49;
    int col = ct * 32 + (lane & 31);
    int kb  = kc * 16 + 8 * (lane >> 5);
    short8 H, L;
#pragma unroll
    for (int j = 0; j < 8; ++j) {
        float v = W0[((size_t)n * 784 + kb + j) * 128 + col];
        unsigned short h = bf16_rne(v);
        H[j] = (short)h;
        L[j] = (short)bf16_rne(v - bf16_to_f(h));
    }
    short8* dst = reinterpret_cast<short8*>(wp + (size_t)((n * 49 + kc) * 4 + ct) * 1024) + lane;
    dst[0]  = H;
    dst[64] = L;
}

// W7: HI only (lo term dropped in L7; est. absmax +~0.01-0.03, threshold 0.26)
__device__ __forceinline__ void pack_w7_body(int tid, const float* __restrict__ W7,
                                             unsigned short* __restrict__ wp) {
    if (tid >= 10 * 8 * 25 * 64) return;
    int lane = tid & 63; int t2 = tid >> 6;
    int ct = t2 % 25; t2 /= 25;
    int kc = t2 % 8;  int n = t2 / 8;
    int col = ct * 32 + (lane & 31);
    int kb  = kc * 16 + 8 * (lane >> 5);
    short8 H;
#pragma unroll
    for (int j = 0; j < 8; ++j) {
        float v = (col < 784) ? W7[((size_t)n * 128 + kb + j) * 784 + col] : 0.f;
        H[j] = (short)bf16_rne(v);
    }
    short8* dst = reinterpret_cast<short8*>(wp + (size_t)((n * 8 + kc) * 25 + ct) * 512) + lane;
    dst[0] = H;
}

__device__ __forceinline__ void pack_w1_body(int tid, const float* __restrict__ W1,
                                             unsigned short* __restrict__ wp) {
    if (tid >= 10 * 8 * 2 * 64) return;
    int lane = tid & 63; int t2 = tid >> 6;
    int ct = t2 % 2; t2 /= 2;
    int kc = t2 % 8; int n = t2 / 8;
    int col = ct * 32 + (lane & 31);
    int kb  = kc * 16 + 8 * (lane >> 5);
    short8 H, L;
#pragma unroll
    for (int j = 0; j < 8; ++j) {
        float v = W1[((size_t)n * 128 + kb + j) * 64 + col];
        unsigned short h = bf16_rne(v);
        H[j] = (short)h;
        L[j] = (short)bf16_rne(v - bf16_to_f(h));
    }
    short8* dst = reinterpret_cast<short8*>(wp + (size_t)((n * 8 + kc) * 2 + ct) * 1024) + lane;
    dst[0]  = H;
    dst[64] = L;
}

__device__ __forceinline__ void pack_w6_body(int tid, const float* __restrict__ W6,
                                             unsigned short* __restrict__ wp) {
    if (tid >= 10 * 4 * 4 * 64) return;
    int lane = tid & 63; int t2 = tid >> 6;
    int ct = t2 % 4; t2 /= 4;
    int kc = t2 % 4; int n = t2 / 4;
    int col = ct * 32 + (lane & 31);
    int kb  = kc * 16 + 8 * (lane >> 5);
    short8 H, L;
#pragma unroll
    for (int j = 0; j < 8; ++j) {
        float v = W6[((size_t)n * 64 + kb + j) * 128 + col];
        unsigned short h = bf16_rne(v);
        H[j] = (short)h;
        L[j] = (short)bf16_rne(v - bf16_to_f(h));
    }
    short8* dst = reinterpret_cast<short8*>(wp + (size_t)((n * 4 + kc) * 4 + ct) * 1024) + lane;
    dst[0]  = H;
    dst[64] = L;
}

__global__ __launch_bounds__(256)
void pack_all_kernel(const float* __restrict__ x,
                     const float* __restrict__ W0, const float* __restrict__ W1,
                     const float* __restrict__ W6, const float* __restrict__ W7,
                     unsigned short* __restrict__ ws_u16) {
    __shared__ float xs[32][113];
    int b = blockIdx.x;
    if (b < PX_BLOCKS) {
        pack_x_body(b, threadIdx.x, x, ws_u16, xs);
    } else if (b < PX_BLOCKS + PW0_BLOCKS) {
        pack_w0_body((b - PX_BLOCKS) * 256 + threadIdx.x, W0, ws_u16 + W0PACK_OFF / 2);
    } else if (b < PX_BLOCKS + PW0_BLOCKS + PW7_BLOCKS) {
        pack_w7_body((b - PX_BLOCKS - PW0_BLOCKS) * 256 + threadIdx.x, W7, ws_u16 + W7PACK_OFF / 2);
    } else if (b < PX_BLOCKS + PW0_BLOCKS + PW7_BLOCKS + PW1_BLOCKS) {
        pack_w1_body((b - PX_BLOCKS - PW0_BLOCKS - PW7_BLOCKS) * 256 + threadIdx.x, W1, ws_u16 + W1PACK_OFF / 2);
    } else {
        pack_w6_body((b - PX_BLOCKS - PW0_BLOCKS - PW7_BLOCKS - PW1_BLOCKS) * 256 + threadIdx.x, W6, ws_u16 + W6PACK_OFF / 2);
    }
}

// ---------------- mid layers (fp32 VALU; r4-proven wave-split) ----------
template<int ID, int OD, int NO, bool RELU>
__device__ __forceinline__ void midlayer(const float* __restrict__ W,
                                         const float* __restrict__ bias,
                                         const float* bufIn, float* bufOut,
                                         int n, int w, int lane) {
    const int o0 = w * NO;
    if (o0 < OD) {
        float acc[NO];
#pragma unroll
        for (int j = 0; j < NO; ++j) acc[j] = bias[n * OD + o0 + j];
        for (int k = 0; k < ID; ++k) {
            float a = bufIn[k * 65 + lane];
            const float* Wk = W + ((size_t)n * ID + k) * OD + o0;
#pragma unroll
            for (int j = 0; j < NO; ++j) acc[j] = fmaf(a, Wk[j], acc[j]);
        }
#pragma unroll
        for (int j = 0; j < NO; ++j) {
            float v = acc[j];
            if (RELU) v = fmaxf(v, 0.f);
            bufOut[(o0 + j) * 65 + lane] = v;
        }
    }
    __syncthreads();
}

#define MFMA32(A, B, C) __builtin_amdgcn_mfma_f32_32x32x16_bf16(A, B, C, 0, 0, 0)

// ---------------- main fused kernel ----------------
// Single 33.3 KB LDS buffer (r10, -9%). Occupancy locked at 4 waves/SIMD by
// VGPR quantum (84 -> 128); grid 5/CU -> 1 tail round at 1/4 capacity.
// Ledger: r4 structure proven; landmines: (256,4) bound -> spill (r5);
// register midlayers (r6); raw-x L0 (r8). r11: W7-lo dropped (L7 24->16
// MFMA/ct, W7 loads & L2 footprint halved).
__global__ __launch_bounds__(256)
void fused_ae_mfma_kernel(const float* __restrict__ B0,
                          const float* __restrict__ B1,
                          const float* __restrict__ W2, const float* __restrict__ B2,
                          const float* __restrict__ W3, const float* __restrict__ B3,
                          const float* __restrict__ W4, const float* __restrict__ B4,
                          const float* __restrict__ W5, const float* __restrict__ B5,
                          const float* __restrict__ B6,
                          const float* __restrict__ B7,
                          const unsigned short* __restrict__ ws_u16,
                          float* __restrict__ out) {
    __shared__ float Hs[128 * 65];    // 33.3 KB single buffer
    unsigned* Hsu = reinterpret_cast<unsigned*>(Hs);

    const int t    = threadIdx.x;
    const int lane = t & 63;
    const int w    = __builtin_amdgcn_readfirstlane(t >> 6);  // wave 0..3

    // XCD swizzle: all 10 nets sharing a y-tile land on the same XCD.
    const int bid = blockIdx.x;
    const int g   = bid & 7;
    const int j8  = bid >> 3;          // 0..159
    const int yb  = (g << 4) + (j8 / 10);
    const int n   = j8 % 10;

    const int cl   = lane & 31;
    const int hf   = lane >> 5;
    const int rtl  = w >> 1;
    const int ct0  = (w & 1) * 2;

    const short8* xp8  = reinterpret_cast<const short8*>(ws_u16);
    const short8* w0p8 = reinterpret_cast<const short8*>(ws_u16 + W0PACK_OFF / 2);
    const short8* w7p8 = reinterpret_cast<const short8*>(ws_u16 + W7PACK_OFF / 2);
    const short8* w1p8 = reinterpret_cast<const short8*>(ws_u16 + W1PACK_OFF / 2);
    const short8* w6p8 = reinterpret_cast<const short8*>(ws_u16 + W6PACK_OFF / 2);

    // ===== Layer 0: x(hi+lo) @ W0(hi+lo), 3-term bf16 split, relu =====
    const int rt = yb * 2 + rtl;
    f32x16 acc0, acc1;
#pragma unroll
    for (int i = 0; i < 16; ++i) { acc0[i] = 0.f; acc1[i] = 0.f; }

    const short8* xA = xp8 + (size_t)rt * 49 * 128 + lane;
    const short8* wB = w0p8 + ((size_t)n * 49 * 4 + ct0) * 128 + lane;

    short8 Ah = xA[0], Al = xA[64];
    short8 Bh0 = wB[0], Bl0 = wB[64], Bh1 = wB[128], Bl1 = wB[192];
    for (int kc = 0; kc < 49; ++kc) {
        short8 nAh, nAl, nBh0, nBl0, nBh1, nBl1;
        if (kc < 48) {
            const short8* xn = xA + (size_t)(kc + 1) * 128;
            const short8* wn = wB + (size_t)(kc + 1) * 512;
            nAh = xn[0]; nAl = xn[64];
            nBh0 = wn[0]; nBl0 = wn[64]; nBh1 = wn[128]; nBl1 = wn[192];
        }
        acc0 = MFMA32(Ah, Bh0, acc0);
        acc0 = MFMA32(Ah, Bl0, acc0);
        acc0 = MFMA32(Al, Bh0, acc0);
        acc1 = MFMA32(Ah, Bh1, acc1);
        acc1 = MFMA32(Ah, Bl1, acc1);
        acc1 = MFMA32(Al, Bh1, acc1);
        if (kc < 48) { Ah = nAh; Al = nAl; Bh0 = nBh0; Bl0 = nBl0; Bh1 = nBh1; Bl1 = nBl1; }
    }
    {
        float b0a = B0[n * 128 + ct0 * 32 + cl];
        float b0b = B0[n * 128 + (ct0 + 1) * 32 + cl];
#pragma unroll
        for (int r2 = 0; r2 < 16; ++r2) {
            int row = rtl * 32 + (r2 & 3) + 8 * (r2 >> 2) + 4 * hf;
            Hsu[(ct0 * 32 + cl) * 65 + row]       = split_pack(fmaxf(acc0[r2] + b0a, 0.f));
            Hsu[((ct0 + 1) * 32 + cl) * 65 + row] = split_pack(fmaxf(acc1[r2] + b0b, 0.f));
        }
    }
    __syncthreads();

    // ===== Layer 1: h0 @ W1 -> h1 (f32, feats 0-63) over h0's region =====
    {
        const int ctl = w & 1;
        short8 a_hi[8], a_lo[8];
        const int r32 = rtl * 32 + cl;
#pragma unroll
        for (int kc = 0; kc < 8; ++kc) {
            int kb = kc * 16 + 8 * hf;
            short8 H, L;
#pragma unroll
            for (int j = 0; j < 8; ++j) {
                unsigned u = Hsu[(kb + j) * 65 + r32];
                H[j] = (short)(u & 0xFFFFu);
                L[j] = (short)(u >> 16);
            }
            a_hi[kc] = H; a_lo[kc] = L;
        }
        f32x16 acc;
#pragma unroll
        for (int i = 0; i < 16; ++i) acc[i] = 0.f;
        const short8* wb = w1p8 + ((size_t)n * 16 + ctl) * 128 + lane;
#pragma unroll
        for (int kc = 0; kc < 8; ++kc) {
            const short8* bp = wb + (size_t)kc * 256;
            short8 Bh = bp[0], Bl = bp[64];
            acc = MFMA32(a_hi[kc], Bh, acc);
            acc = MFMA32(a_hi[kc], Bl, acc);
            acc = MFMA32(a_lo[kc], Bh, acc);
        }
        __syncthreads();   // all h0 reads complete -> buffer reusable for h1
        float bias = B1[n * 64 + ctl * 32 + cl];
#pragma unroll
        for (int r2 = 0; r2 < 16; ++r2) {
            int row = rtl * 32 + (r2 & 3) + 8 * (r2 >> 2) + 4 * hf;
            Hs[(ctl * 32 + cl) * 65 + row] = fmaxf(acc[r2] + bias, 0.f);
        }
    }
    __syncthreads();

    // ===== Layers 2..5 (fp32 VALU, region-hopping within Hs) =====
    midlayer< 64, 12,  3, true >(W2, B2, Hs,           Hs + 64 * 65, n, w, lane); // h1 -> h2
    midlayer< 12,  3,  1, false>(W3, B3, Hs + 64 * 65, Hs + 76 * 65, n, w, lane); // h2 -> h3
    midlayer<  3, 12,  3, true >(W4, B4, Hs + 76 * 65, Hs + 79 * 65, n, w, lane); // h3 -> h4
    midlayer< 12, 64, 16, true >(W5, B5, Hs + 79 * 65, Hs,           n, w, lane); // h4 -> h5 (h1 dead)

    // ===== Layer 6: h5 @ W6 -> h6 (u32, feats 0-127) over whole buffer =====
    {
        short8 a_hi[4], a_lo[4];
        const int r32 = rtl * 32 + cl;
#pragma unroll
        for (int kc = 0; kc < 4; ++kc) {
            int kb = kc * 16 + 8 * hf;
            short8 H, L;
#pragma unroll
            for (int j = 0; j < 8; ++j) {
                float v = Hs[(kb + j) * 65 + r32];
                unsigned short h = bf16_rne(v);
                H[j] = (short)h;
                L[j] = (short)bf16_rne(v - bf16_to_f(h));
            }
            a_hi[kc] = H; a_lo[kc] = L;
        }
        f32x16 acc0b, acc1b;
#pragma unroll
        for (int i = 0; i < 16; ++i) { acc0b[i] = 0.f; acc1b[i] = 0.f; }
        const short8* wb = w6p8 + ((size_t)n * 16 + ct0) * 128 + lane;
#pragma unroll
        for (int kc = 0; kc < 4; ++kc) {
            const short8* bp = wb + (size_t)kc * 512;
            short8 Bh0 = bp[0],   Bl0 = bp[64];
            short8 Bh1 = bp[128], Bl1 = bp[192];
            acc0b = MFMA32(a_hi[kc], Bh0, acc0b);
            acc0b = MFMA32(a_hi[kc], Bl0, acc0b);
            acc0b = MFMA32(a_lo[kc], Bh0, acc0b);
            acc1b = MFMA32(a_hi[kc], Bh1, acc1b);
            acc1b = MFMA32(a_hi[kc], Bl1, acc1b);
            acc1b = MFMA32(a_lo[kc], Bh1, acc1b);
        }
        __syncthreads();   // all h5 reads complete -> buffer reusable for h6
        float b6a = B6[n * 128 + ct0 * 32 + cl];
        float b6b = B6[n * 128 + (ct0 + 1) * 32 + cl];
#pragma unroll
        for (int r2 = 0; r2 < 16; ++r2) {
            int row = rtl * 32 + (r2 & 3) + 8 * (r2 >> 2) + 4 * hf;
            Hsu[(ct0 * 32 + cl) * 65 + row]       = split_pack(fmaxf(acc0b[r2] + b6a, 0.f));
            Hsu[((ct0 + 1) * 32 + cl) * 65 + row] = split_pack(fmaxf(acc1b[r2] + b6b, 0.f));
        }
    }
    __syncthreads();

    // ===== Layer 7: h6(hi+lo) @ W7_hi, tanh, row-sum =====
    short8 a_hi[8], a_lo[8];
    {
        const int r32 = rtl * 32 + cl;
#pragma unroll
        for (int kc = 0; kc < 8; ++kc) {
            int kb = kc * 16 + 8 * hf;
            short8 H, L;
#pragma unroll
            for (int j = 0; j < 8; ++j) {
                unsigned u = Hsu[(kb + j) * 65 + r32];
                H[j] = (short)(u & 0xFFFFu);
                L[j] = (short)(u >> 16);
            }
            a_hi[kc] = H; a_lo[kc] = L;
        }
    }
    __syncthreads();   // all h6 reads complete -> buffer reusable for partials

    float rowsum[16];
#pragma unroll
    for (int i = 0; i < 16; ++i) rowsum[i] = 0.f;

    const short8* w7b = w7p8 + (size_t)n * 8 * 25 * 64 + lane;
    const int ctS = (w & 1) ? 13 : 0;
    const int ctE = (w & 1) ? 25 : 13;
    for (int ct = ctS; ct < ctE; ++ct) {
        f32x16 accA, accB;   // dual chains, 8 deep each
#pragma unroll
        for (int i = 0; i < 16; ++i) { accA[i] = 0.f; accB[i] = 0.f; }
#pragma unroll
        for (int kc = 0; kc < 8; ++kc) {
            short8 Bh = w7b[(size_t)(kc * 25 + ct) * 64];
            accA = MFMA32(a_hi[kc], Bh, accA);
            accB = MFMA32(a_lo[kc], Bh, accB);
        }
        int col = ct * 32 + cl;
        if (col < 784) {
            float bias = B7[n * 784 + col];
#pragma unroll
            for (int r2 = 0; r2 < 16; ++r2)
                rowsum[r2] += fast_tanh(accA[r2] + accB[r2] + bias);
        }
    }

#pragma unroll
    for (int r2 = 0; r2 < 16; ++r2) {
        float s = rowsum[r2];
        s += __shfl_xor(s, 1);  s += __shfl_xor(s, 2);  s += __shfl_xor(s, 4);
        s += __shfl_xor(s, 8);  s += __shfl_xor(s, 16);
        rowsum[r2] = s;
    }

    float* Ps = Hs;    // safe: post-fragload barrier above guards h6 reads
    Ps[t] = 0.f;       // REQUIRED: each wave writes only 32 of its 64 slots below
    __syncthreads();
    if (cl == 0) {
#pragma unroll
        for (int r2 = 0; r2 < 16; ++r2) {
            int row = rtl * 32 + (r2 & 3) + 8 * (r2 >> 2) + 4 * hf;
            Ps[w * 64 + row] = rowsum[r2];
        }
    }
    __syncthreads();
    if (t < 64) {
        float s = Ps[t] + Ps[64 + t] + Ps[128 + t] + Ps[192 + t];
        out[(size_t)(yb * 64 + t) * 10 + n] = s;
    }
}

// ---------------- fp32 fallback if ws too small ----------------
__global__ __launch_bounds__(256)
void fused_ae_fp32_kernel(const float* __restrict__ x,
                          const float* __restrict__ W0, const float* __restrict__ B0,
                          const float* __restrict__ W1, const float* __restrict__ B1,
                          const float* __restrict__ W2, const float* __restrict__ B2,
                          const float* __restrict__ W3, const float* __restrict__ B3,
                          const float* __restrict__ W4, const float* __restrict__ B4,
                          const float* __restrict__ W5, const float* __restrict__ B5,
                          const float* __restrict__ W6, const float* __restrict__ B6,
                          const float* __restrict__ W7, const float* __restrict__ B7,
                          float* __restrict__ out) {
    __shared__ float HsA[128 * 65];
    __shared__ float HsB[64 * 65];
    const int t    = threadIdx.x;
    const int lane = t & 63;
    const int w    = __builtin_amdgcn_readfirstlane(t >> 6);
    const int n    = blockIdx.x;
    const int rowbase = blockIdx.y * 64;

    float acc0[32];
#pragma unroll
    for (int j = 0; j < 32; ++j) acc0[j] = 0.f;
    float* As = HsB;
    const int r   = t >> 2;
    const int kk4 = (t & 3) * 4;
    const float* xrow = x + (size_t)(rowbase + r) * 784;
    for (int kc = 0; kc < 49; ++kc) {
        float4 xv = *(const float4*)(xrow + kc * 16 + kk4);
        As[(kk4 + 0) * 65 + r] = xv.x;
        As[(kk4 + 1) * 65 + r] = xv.y;
        As[(kk4 + 2) * 65 + r] = xv.z;
        As[(kk4 + 3) * 65 + r] = xv.w;
        __syncthreads();
        const float* W0base = W0 + ((size_t)n * 784 + (size_t)kc * 16) * 128 + w * 32;
#pragma unroll
        for (int k = 0; k < 16; ++k) {
            float a = As[k * 65 + lane];
            const float* Wk = W0base + k * 128;
#pragma unroll
            for (int j = 0; j < 32; ++j) acc0[j] = fmaf(a, Wk[j], acc0[j]);
        }
        __syncthreads();
    }
    {
        const float* bb = B0 + n * 128 + w * 32;
#pragma unroll
        for (int j = 0; j < 32; ++j)
            HsA[(w * 32 + j) * 65 + lane] = fmaxf(acc0[j] + bb[j], 0.f);
    }
    __syncthreads();

    midlayer<128, 64, 16, true >(W1, B1, HsA, HsB, n, w, lane);
    midlayer< 64, 12,  3, true >(W2, B2, HsB, HsA, n, w, lane);
    midlayer< 12,  3,  1, false>(W3, B3, HsA, HsB, n, w, lane);
    midlayer<  3, 12,  3, true >(W4, B4, HsB, HsA, n, w, lane);
    midlayer< 12, 64, 16, true >(W5, B5, HsA, HsB, n, w, lane);
    midlayer< 64,128, 32, true >(W6, B6, HsB, HsA, n, w, lane);

    float lane_sum = 0.f;
    const int j0w = w * 196;
    for (int c = 0; c < 7; ++c) {
        const int j0 = j0w + c * 28;
        float acc[28];
        const float* bb = B7 + n * 784 + j0;
#pragma unroll
        for (int j = 0; j < 28; ++j) acc[j] = bb[j];
        for (int k = 0; k < 128; ++k) {
            float a = HsA[k * 65 + lane];
            const float* Wk = W7 + ((size_t)n * 128 + k) * 784 + j0;
#pragma unroll
            for (int j = 0; j < 28; ++j) acc[j] = fmaf(a, Wk[j], acc[j]);
        }
#pragma unroll
        for (int j = 0; j < 28; ++j) lane_sum += fast_tanh(acc[j]);
    }
    float* partial = HsB;
    partial[w * 64 + lane] = lane_sum;
    __syncthreads();
    if (t < 64) {
        float s = partial[t] + partial[64 + t] + partial[128 + t] + partial[192 + t];
        out[(size_t)(rowbase + t) * 10 + n] = s;
    }
}

extern "C" void kernel_launch(void* const* d_in, const int* in_sizes, int n_in,
                              void* d_out, int out_size, void* d_ws, size_t ws_size,
                              hipStream_t stream) {
    (void)in_sizes; (void)n_in; (void)out_size;
    const float* x  = (const float*)d_in[0];
    const float* W0 = (const float*)d_in[1];  const float* B0 = (const float*)d_in[2];
    const float* W1 = (const float*)d_in[3];  const float* B1 = (const float*)d_in[4];
    const float* W2 = (const float*)d_in[5];  const float* B2 = (const float*)d_in[6];
    const float* W3 = (const float*)d_in[7];  const float* B3 = (const float*)d_in[8];
    const float* W4 = (const float*)d_in[9];  const float* B4 = (const float*)d_in[10];
    const float* W5 = (const float*)d_in[11]; const float* B5 = (const float*)d_in[12];
    const float* W6 = (const float*)d_in[13]; const float* B6 = (const float*)d_in[14];
    const float* W7 = (const float*)d_in[15]; const float* B7 = (const float*)d_in[16];
    float* out = (float*)d_out;

    if (ws_size >= TOTAL_WS) {
        unsigned short* ws_u16 = (unsigned short*)d_ws;
        hipLaunchKernelGGL(pack_all_kernel, dim3(PACK_GRID), dim3(256), 0, stream,
                           x, W0, W1, W6, W7, ws_u16);
        hipLaunchKernelGGL(fused_ae_mfma_kernel, dim3(NNETS * (BATCH / 64)), dim3(256), 0, stream,
                           B0, B1, W2, B2, W3, B3, W4, B4, W5, B5, B6, B7, ws_u16, out);
    } else {
        hipLaunchKernelGGL(fused_ae_fp32_kernel, dim3(NNETS, BATCH / 64), dim3(256), 0, stream,
                           x, W0, B0, W1, B1, W2, B2, W3, B3,
                           W4, B4, W5, B5, W6, B6, W7, B7, out);
    }
}

// Round 12
// 221.305 us; speedup vs baseline: 1.2547x; 1.1643x over previous
//
#include <hip/hip_runtime.h>

#define NNETS 10
#define BATCH 8192

typedef __attribute__((ext_vector_type(8)))  short  short8;
typedef __attribute__((ext_vector_type(16))) float  f32x16;

// ---------------- workspace layout (bytes) ----------------
// xpack : [rt(256)][kc(49)][lane(64)][j(8)] bf16          <-- HI ONLY (r12)
// w0pack: [n(10)][kc(49)][ct(4)][hl(2)][lane(64)][j(8)]       (hi+lo kept)
// w7pack: [n(10)][kc(8)][ct(25)][lane(64)][j(8)]          <-- HI ONLY (r11)
// w1pack: [n(10)][kc(8)][ct(2)][hl(2)][lane(64)][j(8)]
// w6pack: [n(10)][kc(4)][ct(4)][hl(2)][lane(64)][j(8)]
// Error budget (absmax, threshold 0.26): W7-lo drop = 0.0625 (measured r11),
// x-lo drop = +~0.03 (measured r7), h6-lo drop = +~0.014 (est) -> ~0.11 total.
#define XPACK_BYTES  (256UL*49*64*8*2)
#define W0PACK_OFF   (XPACK_BYTES)
#define W0PACK_BYTES (10UL*49*4*2*64*8*2)
#define W7PACK_OFF   (W0PACK_OFF + W0PACK_BYTES)
#define W7PACK_BYTES (10UL*8*25*64*8*2)
#define W1PACK_OFF   (W7PACK_OFF + W7PACK_BYTES)
#define W1PACK_BYTES (10UL*8*2*2*64*8*2)
#define W6PACK_OFF   (W1PACK_OFF + W1PACK_BYTES)
#define W6PACK_BYTES (10UL*4*4*2*64*8*2)
#define TOTAL_WS     (W6PACK_OFF + W6PACK_BYTES)

// pack grid ranges (blocks of 256)
#define PX_BLOCKS  (256 * 7)
#define PW0_BLOCKS 490
#define PW7_BLOCKS 500
#define PW1_BLOCKS 40
#define PW6_BLOCKS 40
#define PACK_GRID  (PX_BLOCKS + PW0_BLOCKS + PW7_BLOCKS + PW1_BLOCKS + PW6_BLOCKS)

// ---------------- helpers ----------------
__device__ __forceinline__ float fast_tanh(float x) {
    float e = __expf(2.f * x);
    return 1.f - 2.f * __builtin_amdgcn_rcpf(1.f + e);
}
__device__ __forceinline__ unsigned short bf16_rne(float v) {
    unsigned u = __float_as_uint(v);
    unsigned r = (u + 0x7FFFu + ((u >> 16) & 1u)) >> 16;
    return (unsigned short)r;
}
__device__ __forceinline__ float bf16_to_f(unsigned short h) {
    return __uint_as_float(((unsigned)h) << 16);
}
__device__ __forceinline__ unsigned split_pack(float v) {
    unsigned short h = bf16_rne(v);
    unsigned short l = bf16_rne(v - bf16_to_f(h));
    return (unsigned)h | ((unsigned)l << 16);
}

// ---------------- merged pack kernel ----------------
// x-pack: LDS-staged; coalesced reads AND writes; HI ONLY.
__device__ __forceinline__ void pack_x_body(int blk, int t, const float* __restrict__ x,
                                            unsigned short* __restrict__ xp,
                                            float (*xs)[113]) {
    const int rt = blk / 7;
    const int c  = blk - rt * 7;          // col-chunk 0..6 (112 cols)
#pragma unroll
    for (int it = 0; it < 4; ++it) {
        int f = t + 256 * it;
        if (f < 896) {
            int row  = f / 28;
            int colq = f - row * 28;
            float4 v = *(const float4*)(x + (size_t)(rt * 32 + row) * 784 + c * 112 + colq * 4);
            xs[row][colq * 4 + 0] = v.x;
            xs[row][colq * 4 + 1] = v.y;
            xs[row][colq * 4 + 2] = v.z;
            xs[row][colq * 4 + 3] = v.w;
        }
    }
    __syncthreads();
    const int lane = t & 63;
    const int sub  = t >> 6;
    const int srow = lane & 31;
    const int skb  = 8 * (lane >> 5);
    for (int kcl = sub; kcl < 7; kcl += 4) {
        short8 V;
#pragma unroll
        for (int j = 0; j < 8; ++j)
            V[j] = (short)bf16_rne(xs[srow][kcl * 16 + skb + j]);
        int kc_global = c * 7 + kcl;
        short8* dst = reinterpret_cast<short8*>(xp) + (size_t)(rt * 49 + kc_global) * 64 + lane;
        *dst = V;
    }
}

__device__ __forceinline__ void pack_w0_body(int tid, const float* __restrict__ W0,
                                             unsigned short* __restrict__ wp) {
    if (tid >= 10 * 49 * 4 * 64) return;
    int lane = tid & 63; int t2 = tid >> 6;
    int ct = t2 % 4;  t2 /= 4;
    int kc = t2 % 49; int n = t2 / 49;
    int col = ct * 32 + (lane & 31);
    int kb  = kc * 16 + 8 * (lane >> 5);
    short8 H, L;
#pragma unroll
    for (int j = 0; j < 8; ++j) {
        float v = W0[((size_t)n * 784 + kb + j) * 128 + col];
        unsigned short h = bf16_rne(v);
        H[j] = (short)h;
        L[j] = (short)bf16_rne(v - bf16_to_f(h));
    }
    short8* dst = reinterpret_cast<short8*>(wp + (size_t)((n * 49 + kc) * 4 + ct) * 1024) + lane;
    dst[0]  = H;
    dst[64] = L;
}

// W7: HI only (r11)
__device__ __forceinline__ void pack_w7_body(int tid, const float* __restrict__ W7,
                                             unsigned short* __restrict__ wp) {
    if (tid >= 10 * 8 * 25 * 64) return;
    int lane = tid & 63; int t2 = tid >> 6;
    int ct = t2 % 25; t2 /= 25;
    int kc = t2 % 8;  int n = t2 / 8;
    int col = ct * 32 + (lane & 31);
    int kb  = kc * 16 + 8 * (lane >> 5);
    short8 H;
#pragma unroll
    for (int j = 0; j < 8; ++j) {
        float v = (col < 784) ? W7[((size_t)n * 128 + kb + j) * 784 + col] : 0.f;
        H[j] = (short)bf16_rne(v);
    }
    short8* dst = reinterpret_cast<short8*>(wp + (size_t)((n * 8 + kc) * 25 + ct) * 512) + lane;
    dst[0] = H;
}

__device__ __forceinline__ void pack_w1_body(int tid, const float* __restrict__ W1,
                                             unsigned short* __restrict__ wp) {
    if (tid >= 10 * 8 * 2 * 64) return;
    int lane = tid & 63; int t2 = tid >> 6;
    int ct = t2 % 2; t2 /= 2;
    int kc = t2 % 8; int n = t2 / 8;
    int col = ct * 32 + (lane & 31);
    int kb  = kc * 16 + 8 * (lane >> 5);
    short8 H, L;
#pragma unroll
    for (int j = 0; j < 8; ++j) {
        float v = W1[((size_t)n * 128 + kb + j) * 64 + col];
        unsigned short h = bf16_rne(v);
        H[j] = (short)h;
        L[j] = (short)bf16_rne(v - bf16_to_f(h));
    }
    short8* dst = reinterpret_cast<short8*>(wp + (size_t)((n * 8 + kc) * 2 + ct) * 1024) + lane;
    dst[0]  = H;
    dst[64] = L;
}

__device__ __forceinline__ void pack_w6_body(int tid, const float* __restrict__ W6,
                                             unsigned short* __restrict__ wp) {
    if (tid >= 10 * 4 * 4 * 64) return;
    int lane = tid & 63; int t2 = tid >> 6;
    int ct = t2 % 4; t2 /= 4;
    int kc = t2 % 4; int n = t2 / 4;
    int col = ct * 32 + (lane & 31);
    int kb  = kc * 16 + 8 * (lane >> 5);
    short8 H, L;
#pragma unroll
    for (int j = 0; j < 8; ++j) {
        float v = W6[((size_t)n * 64 + kb + j) * 128 + col];
        unsigned short h = bf16_rne(v);
        H[j] = (short)h;
        L[j] = (short)bf16_rne(v - bf16_to_f(h));
    }
    short8* dst = reinterpret_cast<short8*>(wp + (size_t)((n * 4 + kc) * 4 + ct) * 1024) + lane;
    dst[0]  = H;
    dst[64] = L;
}

__global__ __launch_bounds__(256)
void pack_all_kernel(const float* __restrict__ x,
                     const float* __restrict__ W0, const float* __restrict__ W1,
                     const float* __restrict__ W6, const float* __restrict__ W7,
                     unsigned short* __restrict__ ws_u16) {
    __shared__ float xs[32][113];
    int b = blockIdx.x;
    if (b < PX_BLOCKS) {
        pack_x_body(b, threadIdx.x, x, ws_u16, xs);
    } else if (b < PX_BLOCKS + PW0_BLOCKS) {
        pack_w0_body((b - PX_BLOCKS) * 256 + threadIdx.x, W0, ws_u16 + W0PACK_OFF / 2);
    } else if (b < PX_BLOCKS + PW0_BLOCKS + PW7_BLOCKS) {
        pack_w7_body((b - PX_BLOCKS - PW0_BLOCKS) * 256 + threadIdx.x, W7, ws_u16 + W7PACK_OFF / 2);
    } else if (b < PX_BLOCKS + PW0_BLOCKS + PW7_BLOCKS + PW1_BLOCKS) {
        pack_w1_body((b - PX_BLOCKS - PW0_BLOCKS - PW7_BLOCKS) * 256 + threadIdx.x, W1, ws_u16 + W1PACK_OFF / 2);
    } else {
        pack_w6_body((b - PX_BLOCKS - PW0_BLOCKS - PW7_BLOCKS - PW1_BLOCKS) * 256 + threadIdx.x, W6, ws_u16 + W6PACK_OFF / 2);
    }
}

// ---------------- mid layers (fp32 VALU; r4-proven wave-split) ----------
template<int ID, int OD, int NO, bool RELU>
__device__ __forceinline__ void midlayer(const float* __restrict__ W,
                                         const float* __restrict__ bias,
                                         const float* bufIn, float* bufOut,
                                         int n, int w, int lane) {
    const int o0 = w * NO;
    if (o0 < OD) {
        float acc[NO];
#pragma unroll
        for (int j = 0; j < NO; ++j) acc[j] = bias[n * OD + o0 + j];
        for (int k = 0; k < ID; ++k) {
            float a = bufIn[k * 65 + lane];
            const float* Wk = W + ((size_t)n * ID + k) * OD + o0;
#pragma unroll
            for (int j = 0; j < NO; ++j) acc[j] = fmaf(a, Wk[j], acc[j]);
        }
#pragma unroll
        for (int j = 0; j < NO; ++j) {
            float v = acc[j];
            if (RELU) v = fmaxf(v, 0.f);
            bufOut[(o0 + j) * 65 + lane] = v;
        }
    }
    __syncthreads();
}

#define MFMA32(A, B, C) __builtin_amdgcn_mfma_f32_32x32x16_bf16(A, B, C, 0, 0, 0)

// ---------------- main fused kernel ----------------
// Single 33.3 KB LDS buffer (r10). Occupancy locked at 4 waves/SIMD by VGPR
// quantum. Ledger: landmines = (256,4) bound spill (r5); register midlayers
// (r6); raw-x L0 reads (r8). Precision drops (all measured/bounded, see top):
// x-lo (r12), W7-lo (r11), h6-lo (r12). h0/L1/L6 keep full hi+lo accuracy.
__global__ __launch_bounds__(256)
void fused_ae_mfma_kernel(const float* __restrict__ B0,
                          const float* __restrict__ B1,
                          const float* __restrict__ W2, const float* __restrict__ B2,
                          const float* __restrict__ W3, const float* __restrict__ B3,
                          const float* __restrict__ W4, const float* __restrict__ B4,
                          const float* __restrict__ W5, const float* __restrict__ B5,
                          const float* __restrict__ B6,
                          const float* __restrict__ B7,
                          const unsigned short* __restrict__ ws_u16,
                          float* __restrict__ out) {
    __shared__ float Hs[128 * 65];    // 33.3 KB single buffer
    unsigned* Hsu = reinterpret_cast<unsigned*>(Hs);

    const int t    = threadIdx.x;
    const int lane = t & 63;
    const int w    = __builtin_amdgcn_readfirstlane(t >> 6);  // wave 0..3

    // XCD swizzle: all 10 nets sharing a y-tile land on the same XCD.
    const int bid = blockIdx.x;
    const int g   = bid & 7;
    const int j8  = bid >> 3;          // 0..159
    const int yb  = (g << 4) + (j8 / 10);
    const int n   = j8 % 10;

    const int cl   = lane & 31;
    const int hf   = lane >> 5;
    const int rtl  = w >> 1;
    const int ct0  = (w & 1) * 2;

    const short8* xp8  = reinterpret_cast<const short8*>(ws_u16);
    const short8* w0p8 = reinterpret_cast<const short8*>(ws_u16 + W0PACK_OFF / 2);
    const short8* w7p8 = reinterpret_cast<const short8*>(ws_u16 + W7PACK_OFF / 2);
    const short8* w1p8 = reinterpret_cast<const short8*>(ws_u16 + W1PACK_OFF / 2);
    const short8* w6p8 = reinterpret_cast<const short8*>(ws_u16 + W6PACK_OFF / 2);

    // ===== Layer 0: x_hi @ W0(hi+lo), 2-term split, relu =====
    const int rt = yb * 2 + rtl;
    f32x16 acc0, acc1;
#pragma unroll
    for (int i = 0; i < 16; ++i) { acc0[i] = 0.f; acc1[i] = 0.f; }

    const short8* xA = xp8 + (size_t)rt * 49 * 64 + lane;               // kc stride 64
    const short8* wB = w0p8 + ((size_t)n * 49 * 4 + ct0) * 128 + lane;  // kc stride 512

    short8 Ah = xA[0];
    short8 Bh0 = wB[0], Bl0 = wB[64], Bh1 = wB[128], Bl1 = wB[192];
    for (int kc = 0; kc < 49; ++kc) {
        short8 nAh, nBh0, nBl0, nBh1, nBl1;
        if (kc < 48) {
            const short8* xn = xA + (size_t)(kc + 1) * 64;
            const short8* wn = wB + (size_t)(kc + 1) * 512;
            nAh = xn[0];
            nBh0 = wn[0]; nBl0 = wn[64]; nBh1 = wn[128]; nBl1 = wn[192];
        }
        acc0 = MFMA32(Ah, Bh0, acc0);
        acc0 = MFMA32(Ah, Bl0, acc0);
        acc1 = MFMA32(Ah, Bh1, acc1);
        acc1 = MFMA32(Ah, Bl1, acc1);
        if (kc < 48) { Ah = nAh; Bh0 = nBh0; Bl0 = nBl0; Bh1 = nBh1; Bl1 = nBl1; }
    }
    {
        float b0a = B0[n * 128 + ct0 * 32 + cl];
        float b0b = B0[n * 128 + (ct0 + 1) * 32 + cl];
#pragma unroll
        for (int r2 = 0; r2 < 16; ++r2) {
            int row = rtl * 32 + (r2 & 3) + 8 * (r2 >> 2) + 4 * hf;
            Hsu[(ct0 * 32 + cl) * 65 + row]       = split_pack(fmaxf(acc0[r2] + b0a, 0.f));
            Hsu[((ct0 + 1) * 32 + cl) * 65 + row] = split_pack(fmaxf(acc1[r2] + b0b, 0.f));
        }
    }
    __syncthreads();

    // ===== Layer 1: h0(hi+lo) @ W1(hi+lo 3-term) -> h1 (f32, feats 0-63) =====
    {
        const int ctl = w & 1;
        short8 a_hi[8], a_lo[8];
        const int r32 = rtl * 32 + cl;
#pragma unroll
        for (int kc = 0; kc < 8; ++kc) {
            int kb = kc * 16 + 8 * hf;
            short8 H, L;
#pragma unroll
            for (int j = 0; j < 8; ++j) {
                unsigned u = Hsu[(kb + j) * 65 + r32];
                H[j] = (short)(u & 0xFFFFu);
                L[j] = (short)(u >> 16);
            }
            a_hi[kc] = H; a_lo[kc] = L;
        }
        f32x16 acc;
#pragma unroll
        for (int i = 0; i < 16; ++i) acc[i] = 0.f;
        const short8* wb = w1p8 + ((size_t)n * 16 + ctl) * 128 + lane;
#pragma unroll
        for (int kc = 0; kc < 8; ++kc) {
            const short8* bp = wb + (size_t)kc * 256;
            short8 Bh = bp[0], Bl = bp[64];
            acc = MFMA32(a_hi[kc], Bh, acc);
            acc = MFMA32(a_hi[kc], Bl, acc);
            acc = MFMA32(a_lo[kc], Bh, acc);
        }
        __syncthreads();   // all h0 reads complete -> buffer reusable for h1
        float bias = B1[n * 64 + ctl * 32 + cl];
#pragma unroll
        for (int r2 = 0; r2 < 16; ++r2) {
            int row = rtl * 32 + (r2 & 3) + 8 * (r2 >> 2) + 4 * hf;
            Hs[(ctl * 32 + cl) * 65 + row] = fmaxf(acc[r2] + bias, 0.f);
        }
    }
    __syncthreads();

    // ===== Layers 2..5 (fp32 VALU, region-hopping within Hs) =====
    midlayer< 64, 12,  3, true >(W2, B2, Hs,           Hs + 64 * 65, n, w, lane); // h1 -> h2
    midlayer< 12,  3,  1, false>(W3, B3, Hs + 64 * 65, Hs + 76 * 65, n, w, lane); // h2 -> h3
    midlayer<  3, 12,  3, true >(W4, B4, Hs + 76 * 65, Hs + 79 * 65, n, w, lane); // h3 -> h4
    midlayer< 12, 64, 16, true >(W5, B5, Hs + 79 * 65, Hs,           n, w, lane); // h4 -> h5 (h1 dead)

    // ===== Layer 6: h5(hi+lo) @ W6(hi+lo 3-term) -> h6 (u32) =====
    {
        short8 a_hi[4], a_lo[4];
        const int r32 = rtl * 32 + cl;
#pragma unroll
        for (int kc = 0; kc < 4; ++kc) {
            int kb = kc * 16 + 8 * hf;
            short8 H, L;
#pragma unroll
            for (int j = 0; j < 8; ++j) {
                float v = Hs[(kb + j) * 65 + r32];
                unsigned short h = bf16_rne(v);
                H[j] = (short)h;
                L[j] = (short)bf16_rne(v - bf16_to_f(h));
            }
            a_hi[kc] = H; a_lo[kc] = L;
        }
        f32x16 acc0b, acc1b;
#pragma unroll
        for (int i = 0; i < 16; ++i) { acc0b[i] = 0.f; acc1b[i] = 0.f; }
        const short8* wb = w6p8 + ((size_t)n * 16 + ct0) * 128 + lane;
#pragma unroll
        for (int kc = 0; kc < 4; ++kc) {
            const short8* bp = wb + (size_t)kc * 512;
            short8 Bh0 = bp[0],   Bl0 = bp[64];
            short8 Bh1 = bp[128], Bl1 = bp[192];
            acc0b = MFMA32(a_hi[kc], Bh0, acc0b);
            acc0b = MFMA32(a_hi[kc], Bl0, acc0b);
            acc0b = MFMA32(a_lo[kc], Bh0, acc0b);
            acc1b = MFMA32(a_hi[kc], Bh1, acc1b);
            acc1b = MFMA32(a_hi[kc], Bl1, acc1b);
            acc1b = MFMA32(a_lo[kc], Bh1, acc1b);
        }
        __syncthreads();   // all h5 reads complete -> buffer reusable for h6
        float b6a = B6[n * 128 + ct0 * 32 + cl];
        float b6b = B6[n * 128 + (ct0 + 1) * 32 + cl];
#pragma unroll
        for (int r2 = 0; r2 < 16; ++r2) {
            int row = rtl * 32 + (r2 & 3) + 8 * (r2 >> 2) + 4 * hf;
            Hsu[(ct0 * 32 + cl) * 65 + row]       = split_pack(fmaxf(acc0b[r2] + b6a, 0.f));
            Hsu[((ct0 + 1) * 32 + cl) * 65 + row] = split_pack(fmaxf(acc1b[r2] + b6b, 0.f));
        }
    }
    __syncthreads();

    // ===== Layer 7: h6_hi @ W7_hi, tanh, row-sum =====
    short8 a_hi[8];
    {
        const int r32 = rtl * 32 + cl;
#pragma unroll
        for (int kc = 0; kc < 8; ++kc) {
            int kb = kc * 16 + 8 * hf;
            short8 H;
#pragma unroll
            for (int j = 0; j < 8; ++j)
                H[j] = (short)(Hsu[(kb + j) * 65 + r32] & 0xFFFFu);
            a_hi[kc] = H;
        }
    }
    __syncthreads();   // all h6 reads complete -> buffer reusable for partials

    float rowsum[16];
#pragma unroll
    for (int i = 0; i < 16; ++i) rowsum[i] = 0.f;

    const short8* w7b = w7p8 + (size_t)n * 8 * 25 * 64 + lane;
    const int ctS = (w & 1) ? 13 : 0;
    const int ctE = (w & 1) ? 25 : 13;
    for (int ct = ctS; ct < ctE; ++ct) {
        f32x16 accA, accB;   // dual chains via kc parity: dep depth 4 each
#pragma unroll
        for (int i = 0; i < 16; ++i) { accA[i] = 0.f; accB[i] = 0.f; }
#pragma unroll
        for (int kc = 0; kc < 8; kc += 2) {
            short8 Bh0 = w7b[(size_t)((kc + 0) * 25 + ct) * 64];
            short8 Bh1 = w7b[(size_t)((kc + 1) * 25 + ct) * 64];
            accA = MFMA32(a_hi[kc + 0], Bh0, accA);
            accB = MFMA32(a_hi[kc + 1], Bh1, accB);
        }
        int col = ct * 32 + cl;
        if (col < 784) {
            float bias = B7[n * 784 + col];
#pragma unroll
            for (int r2 = 0; r2 < 16; ++r2)
                rowsum[r2] += fast_tanh(accA[r2] + accB[r2] + bias);
        }
    }

#pragma unroll
    for (int r2 = 0; r2 < 16; ++r2) {
        float s = rowsum[r2];
        s += __shfl_xor(s, 1);  s += __shfl_xor(s, 2);  s += __shfl_xor(s, 4);
        s += __shfl_xor(s, 8);  s += __shfl_xor(s, 16);
        rowsum[r2] = s;
    }

    float* Ps = Hs;    // safe: post-fragload barrier above guards h6 reads
    Ps[t] = 0.f;       // REQUIRED: each wave writes only 32 of its 64 slots below
    __syncthreads();
    if (cl == 0) {
#pragma unroll
        for (int r2 = 0; r2 < 16; ++r2) {
            int row = rtl * 32 + (r2 & 3) + 8 * (r2 >> 2) + 4 * hf;
            Ps[w * 64 + row] = rowsum[r2];
        }
    }
    __syncthreads();
    if (t < 64) {
        float s = Ps[t] + Ps[64 + t] + Ps[128 + t] + Ps[192 + t];
        out[(size_t)(yb * 64 + t) * 10 + n] = s;
    }
}

// ---------------- fp32 fallback if ws too small ----------------
__global__ __launch_bounds__(256)
void fused_ae_fp32_kernel(const float* __restrict__ x,
                          const float* __restrict__ W0, const float* __restrict__ B0,
                          const float* __restrict__ W1, const float* __restrict__ B1,
                          const float* __restrict__ W2, const float* __restrict__ B2,
                          const float* __restrict__ W3, const float* __restrict__ B3,
                          const float* __restrict__ W4, const float* __restrict__ B4,
                          const float* __restrict__ W5, const float* __restrict__ B5,
                          const float* __restrict__ W6, const float* __restrict__ B6,
                          const float* __restrict__ W7, const float* __restrict__ B7,
                          float* __restrict__ out) {
    __shared__ float HsA[128 * 65];
    __shared__ float HsB[64 * 65];
    const int t    = threadIdx.x;
    const int lane = t & 63;
    const int w    = __builtin_amdgcn_readfirstlane(t >> 6);
    const int n    = blockIdx.x;
    const int rowbase = blockIdx.y * 64;

    float acc0[32];
#pragma unroll
    for (int j = 0; j < 32; ++j) acc0[j] = 0.f;
    float* As = HsB;
    const int r   = t >> 2;
    const int kk4 = (t & 3) * 4;
    const float* xrow = x + (size_t)(rowbase + r) * 784;
    for (int kc = 0; kc < 49; ++kc) {
        float4 xv = *(const float4*)(xrow + kc * 16 + kk4);
        As[(kk4 + 0) * 65 + r] = xv.x;
        As[(kk4 + 1) * 65 + r] = xv.y;
        As[(kk4 + 2) * 65 + r] = xv.z;
        As[(kk4 + 3) * 65 + r] = xv.w;
        __syncthreads();
        const float* W0base = W0 + ((size_t)n * 784 + (size_t)kc * 16) * 128 + w * 32;
#pragma unroll
        for (int k = 0; k < 16; ++k) {
            float a = As[k * 65 + lane];
            const float* Wk = W0base + k * 128;
#pragma unroll
            for (int j = 0; j < 32; ++j) acc0[j] = fmaf(a, Wk[j], acc0[j]);
        }
        __syncthreads();
    }
    {
        const float* bb = B0 + n * 128 + w * 32;
#pragma unroll
        for (int j = 0; j < 32; ++j)
            HsA[(w * 32 + j) * 65 + lane] = fmaxf(acc0[j] + bb[j], 0.f);
    }
    __syncthreads();

    midlayer<128, 64, 16, true >(W1, B1, HsA, HsB, n, w, lane);
    midlayer< 64, 12,  3, true >(W2, B2, HsB, HsA, n, w, lane);
    midlayer< 12,  3,  1, false>(W3, B3, HsA, HsB, n, w, lane);
    midlayer<  3, 12,  3, true >(W4, B4, HsB, HsA, n, w, lane);
    midlayer< 12, 64, 16, true >(W5, B5, HsA, HsB, n, w, lane);
    midlayer< 64,128, 32, true >(W6, B6, HsB, HsA, n, w, lane);

    float lane_sum = 0.f;
    const int j0w = w * 196;
    for (int c = 0; c < 7; ++c) {
        const int j0 = j0w + c * 28;
        float acc[28];
        const float* bb = B7 + n * 784 + j0;
#pragma unroll
        for (int j = 0; j < 28; ++j) acc[j] = bb[j];
        for (int k = 0; k < 128; ++k) {
            float a = HsA[k * 65 + lane];
            const float* Wk = W7 + ((size_t)n * 128 + k) * 784 + j0;
#pragma unroll
            for (int j = 0; j < 28; ++j) acc[j] = fmaf(a, Wk[j], acc[j]);
        }
#pragma unroll
        for (int j = 0; j < 28; ++j) lane_sum += fast_tanh(acc[j]);
    }
    float* partial = HsB;
    partial[w * 64 + lane] = lane_sum;
    __syncthreads();
    if (t < 64) {
        float s = partial[t] + partial[64 + t] + partial[128 + t] + partial[192 + t];
        out[(size_t)(rowbase + t) * 10 + n] = s;
    }
}

extern "C" void kernel_launch(void* const* d_in, const int* in_sizes, int n_in,
                              void* d_out, int out_size, void* d_ws, size_t ws_size,
                              hipStream_t stream) {
    (void)in_sizes; (void)n_in; (void)out_size;
    const float* x  = (const float*)d_in[0];
    const float* W0 = (const float*)d_in[1];  const float* B0 = (const float*)d_in[2];
    const float* W1 = (const float*)d_in[3];  const float* B1 = (const float*)d_in[4];
    const float* W2 = (const float*)d_in[5];  const float* B2 = (const float*)d_in[6];
    const float* W3 = (const float*)d_in[7];  const float* B3 = (const float*)d_in[8];
    const float* W4 = (const float*)d_in[9];  const float* B4 = (const float*)d_in[10];
    const float* W5 = (const float*)d_in[11]; const float* B5 = (const float*)d_in[12];
    const float* W6 = (const float*)d_in[13]; const float* B6 = (const float*)d_in[14];
    const float* W7 = (const float*)d_in[15]; const float* B7 = (const float*)d_in[16];
    float* out = (float*)d_out;

    if (ws_size >= TOTAL_WS) {
        unsigned short* ws_u16 = (unsigned short*)d_ws;
        hipLaunchKernelGGL(pack_all_kernel, dim3(PACK_GRID), dim3(256), 0, stream,
                           x, W0, W1, W6, W7, ws_u16);
        hipLaunchKernelGGL(fused_ae_mfma_kernel, dim3(NNETS * (BATCH / 64)), dim3(256), 0, stream,
                           B0, B1, W2, B2, W3, B3, W4, B4, W5, B5, B6, B7, ws_u16, out);
    } else {
        hipLaunchKernelGGL(fused_ae_fp32_kernel, dim3(NNETS, BATCH / 64), dim3(256), 0, stream,
                           x, W0, B0, W1, B1, W2, B2, W3, B3,
                           W4, B4, W5, B5, W6, B6, W7, B7, out);
    }
}